// Round 1
// baseline (311.173 us; speedup 1.0000x reference)
//
#include <hip/hip_runtime.h>
#include <hip/hip_bf16.h>
#include <stdint.h>

typedef __attribute__((ext_vector_type(8))) short short8;
typedef __attribute__((ext_vector_type(4))) float f32x4;
typedef const __attribute__((address_space(1))) uint32_t* gas1_t;
typedef __attribute__((address_space(3))) uint32_t* las3_t;

__device__ __forceinline__ short f2bf(float f) {
  uint32_t u = __builtin_bit_cast(uint32_t, f);
  u += 0x7fffu + ((u >> 16) & 1u);
  return (short)(u >> 16);
}

// ---- convert q,k,v f32 -> bf16 (z selects tensor) ----
__global__ __launch_bounds__(256) void cvt_qkv_k(const float* __restrict__ q,
    const float* __restrict__ k, const float* __restrict__ v,
    short* __restrict__ dst) {
  const long long n = 8388608LL;
  const float* src = (blockIdx.z == 0) ? q : (blockIdx.z == 1) ? k : v;
  long long i = ((long long)blockIdx.x * 256 + threadIdx.x) * 8;
  float4 a = *(const float4*)(src + i);
  float4 b = *(const float4*)(src + i + 4);
  short8 o;
  o[0]=f2bf(a.x); o[1]=f2bf(a.y); o[2]=f2bf(a.z); o[3]=f2bf(a.w);
  o[4]=f2bf(b.x); o[5]=f2bf(b.y); o[6]=f2bf(b.z); o[7]=f2bf(b.w);
  *(short8*)(dst + (long long)blockIdx.z * n + i) = o;
}

// ---- gather the 4 bias vectors into one contiguous buffer ----
__global__ __launch_bounds__(256) void bias_gather_k(const float* b0, const float* b1,
    const float* b2, const float* b3, float* __restrict__ dst) {
  int i = blockIdx.x * 256 + threadIdx.x;
  if (i >= 4096) return;
  int z = i >> 10, j = i & 1023;
  const float* s = (z==0)?b0:(z==1)?b1:(z==2)?b2:b3;
  dst[i] = s[j];
}

// ---- weights: W[K=1024,N=1024] f32 -> Wt[N,K] bf16 (z selects weight) ----
__global__ __launch_bounds__(256) void wt_cvt_k(const float* w0, const float* w1,
    const float* w2, const float* w3, short* __restrict__ dst) {
  __shared__ float t[32][33];
  const float* W = (blockIdx.z==0)?w0:(blockIdx.z==1)?w1:(blockIdx.z==2)?w2:w3;
  short* D = dst + (long long)blockIdx.z * 1048576LL;
  int n0 = blockIdx.x * 32, k0 = blockIdx.y * 32;
  int tx = threadIdx.x, ty = threadIdx.y;
  #pragma unroll
  for (int i = 0; i < 4; ++i)
    t[ty + 8*i][tx] = W[(long long)(k0 + ty + 8*i) * 1024 + n0 + tx];
  __syncthreads();
  #pragma unroll
  for (int i = 0; i < 4; ++i)
    D[(long long)(n0 + ty + 8*i) * 1024 + k0 + tx] = f2bf(t[tx][ty + 8*i]);
}

// ---- bf16 transpose [2048,1024] -> [1024,2048], batched over z ----
__global__ __launch_bounds__(256) void tr_bf16_k(const short* __restrict__ in,
    short* __restrict__ out, long long sIn, long long sOut) {
  __shared__ short t[32][33];
  in  += (long long)blockIdx.z * sIn;
  out += (long long)blockIdx.z * sOut;
  int c0 = blockIdx.x * 32, r0 = blockIdx.y * 32;
  int tx = threadIdx.x, ty = threadIdx.y;
  #pragma unroll
  for (int i = 0; i < 4; ++i)
    t[ty + 8*i][tx] = in[(long long)(r0 + ty + 8*i) * 1024 + c0 + tx];
  __syncthreads();
  #pragma unroll
  for (int i = 0; i < 4; ++i)
    out[(long long)(c0 + ty + 8*i) * 2048 + r0 + tx] = t[tx][ty + 8*i];
}

// ---- row softmax: f32 [rows,2048] -> bf16 [rows,2048], one block per row ----
__global__ __launch_bounds__(256) void softmax_k(const float* __restrict__ S,
                                                 short* __restrict__ P) {
  const long long row = blockIdx.x;
  const float* s = S + row * 2048;
  short* p = P + row * 2048;
  const int t = threadIdx.x;
  float v[8];
  float4 a = *(const float4*)(s + t*8);
  float4 b = *(const float4*)(s + t*8 + 4);
  v[0]=a.x; v[1]=a.y; v[2]=a.z; v[3]=a.w; v[4]=b.x; v[5]=b.y; v[6]=b.z; v[7]=b.w;
  float m = v[0];
  #pragma unroll
  for (int j = 1; j < 8; ++j) m = fmaxf(m, v[j]);
  #pragma unroll
  for (int off = 32; off > 0; off >>= 1) m = fmaxf(m, __shfl_down(m, off, 64));
  __shared__ float rmax[4], rsum[4];
  int wv = t >> 6, ln = t & 63;
  if (ln == 0) rmax[wv] = m;
  __syncthreads();
  m = fmaxf(fmaxf(rmax[0], rmax[1]), fmaxf(rmax[2], rmax[3]));
  float e[8], sum = 0.f;
  #pragma unroll
  for (int j = 0; j < 8; ++j) { e[j] = exp2f((v[j] - m) * 1.44269504f); sum += e[j]; }
  #pragma unroll
  for (int off = 32; off > 0; off >>= 1) sum += __shfl_down(sum, off, 64);
  if (ln == 0) rsum[wv] = sum;
  __syncthreads();
  float inv = 1.0f / (rsum[0] + rsum[1] + rsum[2] + rsum[3]);
  short8 o;
  #pragma unroll
  for (int j = 0; j < 8; ++j) o[j] = f2bf(e[j] * inv);
  *(short8*)(p + t*8) = o;
}

// ---- GEMM: C[M,N] = scale * (A[M,K] @ Bt[N,K]^T) + bias[N]
// A,Bt bf16 row-major (lda=ldb=K), C bf16 or f32 (ldc=N), batched over z.
// m97 structure: 128x128 tile, BK=32, 4 waves (2x2 of 64x64), 16x16x32 MFMA,
// global_load_lds width 16.
template<int OUT_BF16>
__global__ __launch_bounds__(256) void gemm_bt_k(const short* __restrict__ A,
    const short* __restrict__ Bt, void* __restrict__ Cv,
    const float* __restrict__ bias,
    int M, int N, int K, long long sA, long long sB, long long sC,
    long long sBias, float scale)
{
  __shared__ short ldsA[128*32];
  __shared__ short ldsB[128*32];
  const int z = blockIdx.z;
  A  += (long long)z * sA;
  Bt += (long long)z * sB;
  const int bm = blockIdx.y * 128;
  const int bn = blockIdx.x * 128;
  const int tid  = threadIdx.x;
  const int wave = tid >> 6, lane = tid & 63;
  const int wm = (wave >> 1) * 64, wn = (wave & 1) * 64;
  const int lr = lane & 15, lk = lane >> 4;

  // staging: wave w covers tile rows [32w,32w+32); lane i -> row 32w+(i>>2), k-chunk (i&3)*8
  const int srow = wave * 32 + (lane >> 2);
  const int skk  = (lane & 3) * 8;
  const short* gA0 = A  + (long long)(bm + srow) * K + skk;
  const short* gB0 = Bt + (long long)(bn + srow) * K + skk;
  const long long rstep16 = 16LL * K;
  las3_t lA0 = (las3_t)&ldsA[wave*1024];
  las3_t lA1 = (las3_t)&ldsA[wave*1024 + 512];
  las3_t lB0 = (las3_t)&ldsB[wave*1024];
  las3_t lB1 = (las3_t)&ldsB[wave*1024 + 512];

  f32x4 acc[4][4] = {};

  for (int k0 = 0; k0 < K; k0 += 32) {
    __builtin_amdgcn_global_load_lds((gas1_t)(gA0 + k0),           lA0, 16, 0, 0);
    __builtin_amdgcn_global_load_lds((gas1_t)(gA0 + k0 + rstep16), lA1, 16, 0, 0);
    __builtin_amdgcn_global_load_lds((gas1_t)(gB0 + k0),           lB0, 16, 0, 0);
    __builtin_amdgcn_global_load_lds((gas1_t)(gB0 + k0 + rstep16), lB1, 16, 0, 0);
    __syncthreads();
    short8 af[4], bfr[4];
    #pragma unroll
    for (int mi = 0; mi < 4; ++mi)
      af[mi] = *(const short8*)&ldsA[(wm + mi*16 + lr) * 32 + lk*8];
    #pragma unroll
    for (int ni = 0; ni < 4; ++ni)
      bfr[ni] = *(const short8*)&ldsB[(wn + ni*16 + lr) * 32 + lk*8];
    #pragma unroll
    for (int mi = 0; mi < 4; ++mi)
      #pragma unroll
      for (int ni = 0; ni < 4; ++ni)
        acc[mi][ni] = __builtin_amdgcn_mfma_f32_16x16x32_bf16(af[mi], bfr[ni],
                                                              acc[mi][ni], 0, 0, 0);
    __syncthreads();
  }

  const float* bz = bias ? (bias + (long long)z * sBias) : nullptr;
  #pragma unroll
  for (int mi = 0; mi < 4; ++mi) {
    const int row = bm + wm + mi*16 + lk*4;
    #pragma unroll
    for (int ni = 0; ni < 4; ++ni) {
      const int col = bn + wn + ni*16 + lr;
      const float bval = bz ? bz[col] : 0.f;
      #pragma unroll
      for (int r = 0; r < 4; ++r) {
        float val = acc[mi][ni][r] * scale + bval;
        if (OUT_BF16)
          ((short*)Cv)[(long long)z*sC + (long long)(row + r) * N + col] = f2bf(val);
        else
          ((float*)Cv)[(long long)z*sC + (long long)(row + r) * N + col] = val;
      }
    }
  }
}

extern "C" void kernel_launch(void* const* d_in, const int* in_sizes, int n_in,
                              void* d_out, int out_size, void* d_ws, size_t ws_size,
                              hipStream_t stream) {
  const float* q  = (const float*)d_in[0];
  const float* k  = (const float*)d_in[1];
  const float* v  = (const float*)d_in[2];
  // d_in[3] = mask (unused by the reference)
  const float* Wq = (const float*)d_in[4];
  const float* bq = (const float*)d_in[5];
  const float* Wk = (const float*)d_in[6];
  const float* bk = (const float*)d_in[7];
  const float* Wv = (const float*)d_in[8];
  const float* bv = (const float*)d_in[9];
  const float* Wo = (const float*)d_in[10];
  const float* bo = (const float*)d_in[11];

  // ws layout (bytes), peak ~176.2 MB with lifetime-based reuse:
  char* w = (char*)d_ws;
  short* Wt     = (short*)(w);                  // [4][1024][1024] bf16 (W^T)  8,388,608
  float* biasb  = (float*)(w + 8388608);        // [4][1024] f32                  16,384
  short* QKV    = (short*)(w + 8404992);        // Q,K,V bf16 [3][4,2048,1024] 50,331,648
  short* qkvbf  = (short*)(w + 58736640);       // q,k,v bf16 (dies after proj) 50,331,648
  float* scores = (float*)(w + 58736640);       // [4,2048,2048] f32 (reuses ^) 67,108,864
  short* P      = (short*)(w + 125845504);      // [4,2048,2048] bf16          33,554,432
  short* Vt     = (short*)(w + 159399936);      // [4,1024,2048] bf16          16,777,216
  short* x      = (short*)(w + 58736640);       // [4,2048,1024] bf16 (reuses scores)
  short* xt     = (short*)(w + 75513856);       // [4,1024,2048] bf16 (reuses scores)

  short* Qp = QKV;
  short* Kp = QKV + 8388608LL;
  short* Vp = QKV + 16777216LL;

  // 1) convert inputs + weights, gather biases
  cvt_qkv_k<<<dim3(4096,1,3), 256, 0, stream>>>(q, k, v, qkvbf);
  bias_gather_k<<<dim3(16), 256, 0, stream>>>(bq, bk, bv, bo, biasb);
  wt_cvt_k<<<dim3(32,32,4), dim3(32,8), 0, stream>>>(Wq, Wk, Wv, Wo, Wt);

  // 2) projections: [8192,1024] = qkv @ W + b   (z = q/k/v)
  gemm_bt_k<1><<<dim3(8,64,3), 256, 0, stream>>>(qkvbf, Wt, QKV, biasb,
      8192, 1024, 1024, 8388608LL, 1048576LL, 8388608LL, 1024LL, 1.0f);

  // 3) V^T per batch for the PV GEMM's B-operand
  tr_bf16_k<<<dim3(32,64,4), dim3(32,8), 0, stream>>>(Vp, Vt, 2097152LL, 2097152LL);

  // 4) scores = Q @ K^T / 32  (f32, per batch)
  gemm_bt_k<0><<<dim3(16,16,4), 256, 0, stream>>>(Qp, Kp, scores, nullptr,
      2048, 2048, 1024, 2097152LL, 2097152LL, 4194304LL, 0LL, 0.03125f);

  // 5) P = softmax_rows(scores) -> bf16
  softmax_k<<<dim3(8192), 256, 0, stream>>>(scores, P);

  // 6) x = P @ V  (bf16)
  gemm_bt_k<1><<<dim3(8,16,4), 256, 0, stream>>>(P, Vt, x, nullptr,
      2048, 1024, 2048, 4194304LL, 2097152LL, 2097152LL, 0LL, 1.0f);

  // 7) xt = x^T per batch; reshape(x^T) is then a plain [2048,1024] row-major matrix
  tr_bf16_k<<<dim3(32,64,4), dim3(32,8), 0, stream>>>(x, xt, 2097152LL, 2097152LL);

  // 8) out = reshape(x^T) @ Wo + bo  (f32 out)
  gemm_bt_k<0><<<dim3(8,16,4), 256, 0, stream>>>(xt, Wt + 3145728LL, (float*)d_out,
      biasb + 3072, 2048, 1024, 1024, 2097152LL, 0LL, 2097152LL, 0LL, 1.0f);
}

// Round 2
// 279.550 us; speedup vs baseline: 1.1131x; 1.1131x over previous
//
#include <hip/hip_runtime.h>
#include <hip/hip_bf16.h>
#include <stdint.h>

typedef __attribute__((ext_vector_type(8))) short short8;
typedef __attribute__((ext_vector_type(4))) float f32x4;
typedef const __attribute__((address_space(1))) uint32_t* gas1_t;
typedef __attribute__((address_space(3))) uint32_t* las3_t;

__device__ __forceinline__ short f2bf(float f) {
  uint32_t u = __builtin_bit_cast(uint32_t, f);
  u += 0x7fffu + ((u >> 16) & 1u);
  return (short)(u >> 16);
}

// ---- convert q,k,v f32 -> bf16 (z selects tensor) ----
__global__ __launch_bounds__(256) void cvt_qkv_k(const float* __restrict__ q,
    const float* __restrict__ k, const float* __restrict__ v,
    short* __restrict__ dst) {
  const long long n = 8388608LL;
  const float* src = (blockIdx.z == 0) ? q : (blockIdx.z == 1) ? k : v;
  long long i = ((long long)blockIdx.x * 256 + threadIdx.x) * 8;
  float4 a = *(const float4*)(src + i);
  float4 b = *(const float4*)(src + i + 4);
  short8 o;
  o[0]=f2bf(a.x); o[1]=f2bf(a.y); o[2]=f2bf(a.z); o[3]=f2bf(a.w);
  o[4]=f2bf(b.x); o[5]=f2bf(b.y); o[6]=f2bf(b.z); o[7]=f2bf(b.w);
  *(short8*)(dst + (long long)blockIdx.z * n + i) = o;
}

// ---- gather the 4 bias vectors into one contiguous buffer ----
__global__ __launch_bounds__(256) void bias_gather_k(const float* b0, const float* b1,
    const float* b2, const float* b3, float* __restrict__ dst) {
  int i = blockIdx.x * 256 + threadIdx.x;
  if (i >= 4096) return;
  int z = i >> 10, j = i & 1023;
  const float* s = (z==0)?b0:(z==1)?b1:(z==2)?b2:b3;
  dst[i] = s[j];
}

// ---- weights: W[K=1024,N=1024] f32 -> Wt[N,K] bf16 (z selects weight) ----
__global__ __launch_bounds__(256) void wt_cvt_k(const float* w0, const float* w1,
    const float* w2, const float* w3, short* __restrict__ dst) {
  __shared__ float t[32][33];
  const float* W = (blockIdx.z==0)?w0:(blockIdx.z==1)?w1:(blockIdx.z==2)?w2:w3;
  short* D = dst + (long long)blockIdx.z * 1048576LL;
  int n0 = blockIdx.x * 32, k0 = blockIdx.y * 32;
  int tx = threadIdx.x, ty = threadIdx.y;
  #pragma unroll
  for (int i = 0; i < 4; ++i)
    t[ty + 8*i][tx] = W[(long long)(k0 + ty + 8*i) * 1024 + n0 + tx];
  __syncthreads();
  #pragma unroll
  for (int i = 0; i < 4; ++i)
    D[(long long)(n0 + ty + 8*i) * 1024 + k0 + tx] = f2bf(t[tx][ty + 8*i]);
}

// ---- bf16 transpose [2048,1024] -> [1024,2048], batched over z ----
__global__ __launch_bounds__(256) void tr_bf16_k(const short* __restrict__ in,
    short* __restrict__ out, long long sIn, long long sOut) {
  __shared__ short t[32][33];
  in  += (long long)blockIdx.z * sIn;
  out += (long long)blockIdx.z * sOut;
  int c0 = blockIdx.x * 32, r0 = blockIdx.y * 32;
  int tx = threadIdx.x, ty = threadIdx.y;
  #pragma unroll
  for (int i = 0; i < 4; ++i)
    t[ty + 8*i][tx] = in[(long long)(r0 + ty + 8*i) * 1024 + c0 + tx];
  __syncthreads();
  #pragma unroll
  for (int i = 0; i < 4; ++i)
    out[(long long)(c0 + ty + 8*i) * 2048 + r0 + tx] = t[tx][ty + 8*i];
}

// ---- row softmax: f32 [rows,2048] -> bf16 [rows,2048], one block per row ----
__global__ __launch_bounds__(256) void softmax_k(const float* __restrict__ S,
                                                 short* __restrict__ P) {
  const long long row = blockIdx.x;
  const float* s = S + row * 2048;
  short* p = P + row * 2048;
  const int t = threadIdx.x;
  float v[8];
  float4 a = *(const float4*)(s + t*8);
  float4 b = *(const float4*)(s + t*8 + 4);
  v[0]=a.x; v[1]=a.y; v[2]=a.z; v[3]=a.w; v[4]=b.x; v[5]=b.y; v[6]=b.z; v[7]=b.w;
  float m = v[0];
  #pragma unroll
  for (int j = 1; j < 8; ++j) m = fmaxf(m, v[j]);
  #pragma unroll
  for (int off = 32; off > 0; off >>= 1) m = fmaxf(m, __shfl_down(m, off, 64));
  __shared__ float rmax[4], rsum[4];
  int wv = t >> 6, ln = t & 63;
  if (ln == 0) rmax[wv] = m;
  __syncthreads();
  m = fmaxf(fmaxf(rmax[0], rmax[1]), fmaxf(rmax[2], rmax[3]));
  float e[8], sum = 0.f;
  #pragma unroll
  for (int j = 0; j < 8; ++j) { e[j] = exp2f((v[j] - m) * 1.44269504f); sum += e[j]; }
  #pragma unroll
  for (int off = 32; off > 0; off >>= 1) sum += __shfl_down(sum, off, 64);
  if (ln == 0) rsum[wv] = sum;
  __syncthreads();
  float inv = 1.0f / (rsum[0] + rsum[1] + rsum[2] + rsum[3]);
  short8 o;
  #pragma unroll
  for (int j = 0; j < 8; ++j) o[j] = f2bf(e[j] * inv);
  *(short8*)(p + t*8) = o;
}

// ============================================================================
// 256x256 8-phase GEMM (T2 swizzle + T3/T4 counted vmcnt + T5 setprio)
// C[M,N] = scale*(A[M,K] @ Bt[N,K]^T) + bias[N]; bf16 in, bf16/f32 out.
// 512 threads = 8 waves (2 M x 4 N), per-wave 128x64 out, BK=64, LDS 128 KiB.
// LDS granule swizzle: LDS(row, g) holds global (row, g ^ (row&7)); staged via
// pre-swizzled global source (linear global_load_lds dest), read with same XOR.
// Per group g (4 phases): p1 reads A0-3+Bq1, stages Aodd(g+1); p2 reads Bq2,
// stages Aeven(g+2); p3 reads A4-7, stages B0(g+2); p4 stages B1(g+2),
// vmcnt(6) [3 half-tiles in flight], barrier. Stage targets are always regions
// whose last ds_read was in a prior phase (>=1 barrier between).
// ============================================================================
#define MFMA16(d, a_, b_) d = __builtin_amdgcn_mfma_f32_16x16x32_bf16(a_, b_, d, 0, 0, 0)

template<int OUT_BF16>
__global__ __launch_bounds__(512, 2) void gemm8_k(const short* __restrict__ A,
    const short* __restrict__ Bt, void* __restrict__ Cv,
    const float* __restrict__ bias,
    int M, int N, int K, long long sA, long long sB, long long sC,
    long long sBias, float scale)
{
  __shared__ __align__(16) short lds[2][2][256*64];  // [buf][A/B][row*64+col]
  const int z = blockIdx.z;
  A  += (long long)z * sA;
  Bt += (long long)z * sB;
  const int bm = blockIdx.y * 256;
  const int bn = blockIdx.x * 256;
  const int tid  = threadIdx.x;
  const int w    = tid >> 6, lane = tid & 63;
  const int wr   = w >> 2,   wc   = w & 3;     // wave -> (row half, col quarter)
  const int lr   = lane & 15, lk  = lane >> 4;

  // read-side swizzled granule offsets (shorts) for ks=0,1
  const int rsw0 = ((lk    ) ^ (lr & 7)) * 8;
  const int rsw1 = ((lk + 4) ^ (lr & 7)) * 8;

  // stage-side: region i covers tile rows [i*64, i*64+64); lane covers row
  // i*64 + w*8 + (lane>>3), source granule pre-swizzled by (row&7)=(lane>>3)&7
  const int srow = w * 8 + (lane >> 3);
  const int swc  = ((lane & 7) ^ ((lane >> 3) & 7)) * 8;
  const short* gA[4]; const short* gB[4];
  #pragma unroll
  for (int i = 0; i < 4; ++i) {
    gA[i] = A  + (long long)(bm + i*64 + srow) * K + swc;
    gB[i] = Bt + (long long)(bn + i*64 + srow) * K + swc;
  }

  #define STG(buf, ab, i, kt) \
    __builtin_amdgcn_global_load_lds((gas1_t)(((ab) ? gB : gA)[i] + (long long)(kt)*64), \
        (las3_t)&lds[buf][ab][(i)*4096 + w*512], 16, 0, 0)
  #define RDA(buf, mi, ks) (*(const short8*)&lds[buf][0][(wr*128 + (mi)*16 + lr)*64 + ((ks) ? rsw1 : rsw0)])
  #define RDB(buf, ni, ks) (*(const short8*)&lds[buf][1][(wc*64  + (ni)*16 + lr)*64 + ((ks) ? rsw1 : rsw0)])
  #define LGKM0 do { asm volatile("s_waitcnt lgkmcnt(0)" ::: "memory"); \
                     __builtin_amdgcn_sched_barrier(0); } while (0)

  f32x4 acc[8][4] = {};
  const int nt = K >> 6;

  // prologue: tile0 full (8) + tile1 Aeven,B0,B1 (6); tile0 forced complete
  #pragma unroll
  for (int i = 0; i < 4; ++i) STG(0, 0, i, 0);
  #pragma unroll
  for (int i = 0; i < 4; ++i) STG(0, 1, i, 0);
  STG(1, 0, 0, 1); STG(1, 0, 2, 1);   // Aeven(1)
  STG(1, 1, 0, 1); STG(1, 1, 1, 1);   // B0(1)
  STG(1, 1, 2, 1); STG(1, 1, 3, 1);   // B1(1)
  asm volatile("s_waitcnt vmcnt(6)" ::: "memory");
  __builtin_amdgcn_s_barrier();

  for (int g = 0; g < nt; ++g) {
    const int b = g & 1, nb = b ^ 1;
    short8 aR[4][2], bR[4][2];
    // ---- phase 1: quadrant mi0-3 x ni0-1 ----
    #pragma unroll
    for (int mi = 0; mi < 4; ++mi) { aR[mi][0] = RDA(b, mi, 0); aR[mi][1] = RDA(b, mi, 1); }
    #pragma unroll
    for (int ni = 0; ni < 2; ++ni) { bR[ni][0] = RDB(b, ni, 0); bR[ni][1] = RDB(b, ni, 1); }
    if (g + 1 < nt) { STG(nb, 0, 1, g+1); STG(nb, 0, 3, g+1); }  // Aodd(g+1)
    __builtin_amdgcn_s_barrier();
    LGKM0;
    __builtin_amdgcn_s_setprio(1);
    #pragma unroll
    for (int mi = 0; mi < 4; ++mi)
      #pragma unroll
      for (int ni = 0; ni < 2; ++ni) {
        MFMA16(acc[mi][ni], aR[mi][0], bR[ni][0]);
        MFMA16(acc[mi][ni], aR[mi][1], bR[ni][1]);
      }
    __builtin_amdgcn_s_setprio(0);
    __builtin_amdgcn_s_barrier();
    // ---- phase 2: quadrant mi0-3 x ni2-3 ----
    #pragma unroll
    for (int ni = 2; ni < 4; ++ni) { bR[ni][0] = RDB(b, ni, 0); bR[ni][1] = RDB(b, ni, 1); }
    if (g + 2 < nt) { STG(b, 0, 0, g+2); STG(b, 0, 2, g+2); }    // Aeven(g+2)
    __builtin_amdgcn_s_barrier();
    LGKM0;
    __builtin_amdgcn_s_setprio(1);
    #pragma unroll
    for (int mi = 0; mi < 4; ++mi)
      #pragma unroll
      for (int ni = 2; ni < 4; ++ni) {
        MFMA16(acc[mi][ni], aR[mi][0], bR[ni][0]);
        MFMA16(acc[mi][ni], aR[mi][1], bR[ni][1]);
      }
    __builtin_amdgcn_s_setprio(0);
    __builtin_amdgcn_s_barrier();
    // ---- phase 3: quadrant mi4-7 x ni0-1 ----
    #pragma unroll
    for (int mi = 0; mi < 4; ++mi) { aR[mi][0] = RDA(b, mi+4, 0); aR[mi][1] = RDA(b, mi+4, 1); }
    if (g + 2 < nt) { STG(b, 1, 0, g+2); STG(b, 1, 1, g+2); }    // B0(g+2)
    __builtin_amdgcn_s_barrier();
    LGKM0;
    __builtin_amdgcn_s_setprio(1);
    #pragma unroll
    for (int mi = 0; mi < 4; ++mi)
      #pragma unroll
      for (int ni = 0; ni < 2; ++ni) {
        MFMA16(acc[mi+4][ni], aR[mi][0], bR[ni][0]);
        MFMA16(acc[mi+4][ni], aR[mi][1], bR[ni][1]);
      }
    __builtin_amdgcn_s_setprio(0);
    __builtin_amdgcn_s_barrier();
    // ---- phase 4: quadrant mi4-7 x ni2-3 ----
    if (g + 2 < nt) { STG(b, 1, 2, g+2); STG(b, 1, 3, g+2); }    // B1(g+2)
    __builtin_amdgcn_s_setprio(1);
    #pragma unroll
    for (int mi = 0; mi < 4; ++mi)
      #pragma unroll
      for (int ni = 2; ni < 4; ++ni) {
        MFMA16(acc[mi+4][ni], aR[mi][0], bR[ni][0]);
        MFMA16(acc[mi+4][ni], aR[mi][1], bR[ni][1]);
      }
    __builtin_amdgcn_s_setprio(0);
    if (g + 1 < nt) {
      if (g + 2 < nt) asm volatile("s_waitcnt vmcnt(6)" ::: "memory");
      else            asm volatile("s_waitcnt vmcnt(0)" ::: "memory");
    }
    __builtin_amdgcn_s_barrier();
  }

  // ---- epilogue ----
  const float* bz = bias ? (bias + (long long)z * sBias) : nullptr;
  #pragma unroll
  for (int mi = 0; mi < 8; ++mi) {
    const int row = bm + wr*128 + mi*16 + lk*4;
    #pragma unroll
    for (int ni = 0; ni < 4; ++ni) {
      const int col = bn + wc*64 + ni*16 + lr;
      const float bval = bz ? bz[col] : 0.f;
      #pragma unroll
      for (int r = 0; r < 4; ++r) {
        float val = acc[mi][ni][r] * scale + bval;
        if (OUT_BF16)
          ((short*)Cv)[(long long)z*sC + (long long)(row + r) * N + col] = f2bf(val);
        else
          ((float*)Cv)[(long long)z*sC + (long long)(row + r) * N + col] = val;
      }
    }
  }
  #undef STG
  #undef RDA
  #undef RDB
  #undef LGKM0
}

extern "C" void kernel_launch(void* const* d_in, const int* in_sizes, int n_in,
                              void* d_out, int out_size, void* d_ws, size_t ws_size,
                              hipStream_t stream) {
  const float* q  = (const float*)d_in[0];
  const float* k  = (const float*)d_in[1];
  const float* v  = (const float*)d_in[2];
  // d_in[3] = mask (unused by the reference)
  const float* Wq = (const float*)d_in[4];
  const float* bq = (const float*)d_in[5];
  const float* Wk = (const float*)d_in[6];
  const float* bk = (const float*)d_in[7];
  const float* Wv = (const float*)d_in[8];
  const float* bv = (const float*)d_in[9];
  const float* Wo = (const float*)d_in[10];
  const float* bo = (const float*)d_in[11];

  // ws layout (bytes), peak ~176.2 MB with lifetime-based reuse:
  char* w = (char*)d_ws;
  short* Wt     = (short*)(w);                  // [4][1024][1024] bf16 (W^T)  8,388,608
  float* biasb  = (float*)(w + 8388608);        // [4][1024] f32                  16,384
  short* QKV    = (short*)(w + 8404992);        // Q,K,V bf16 [3][4,2048,1024] 50,331,648
  short* qkvbf  = (short*)(w + 58736640);       // q,k,v bf16 (dies after proj) 50,331,648
  float* scores = (float*)(w + 58736640);       // [4,2048,2048] f32 (reuses ^) 67,108,864
  short* P      = (short*)(w + 125845504);      // [4,2048,2048] bf16          33,554,432
  short* Vt     = (short*)(w + 159399936);      // [4,1024,2048] bf16          16,777,216
  short* x      = (short*)(w + 58736640);       // [4,2048,1024] bf16 (reuses scores)
  short* xt     = (short*)(w + 75513856);       // [4,1024,2048] bf16 (reuses scores)

  short* Qp = QKV;
  short* Kp = QKV + 8388608LL;
  short* Vp = QKV + 16777216LL;

  // 1) convert inputs + weights, gather biases
  cvt_qkv_k<<<dim3(4096,1,3), 256, 0, stream>>>(q, k, v, qkvbf);
  bias_gather_k<<<dim3(16), 256, 0, stream>>>(bq, bk, bv, bo, biasb);
  wt_cvt_k<<<dim3(32,32,4), dim3(32,8), 0, stream>>>(Wq, Wk, Wv, Wo, Wt);

  // 2) projections: [8192,1024] = qkv @ W + b   (z = q/k/v)
  gemm8_k<1><<<dim3(4,32,3), 512, 0, stream>>>(qkvbf, Wt, QKV, biasb,
      8192, 1024, 1024, 8388608LL, 1048576LL, 8388608LL, 1024LL, 1.0f);

  // 3) V^T per batch for the PV GEMM's B-operand
  tr_bf16_k<<<dim3(32,64,4), dim3(32,8), 0, stream>>>(Vp, Vt, 2097152LL, 2097152LL);

  // 4) scores = Q @ K^T / 32  (f32, per batch)
  gemm8_k<0><<<dim3(8,8,4), 512, 0, stream>>>(Qp, Kp, scores, nullptr,
      2048, 2048, 1024, 2097152LL, 2097152LL, 4194304LL, 0LL, 0.03125f);

  // 5) P = softmax_rows(scores) -> bf16
  softmax_k<<<dim3(8192), 256, 0, stream>>>(scores, P);

  // 6) x = P @ V  (bf16)
  gemm8_k<1><<<dim3(4,8,4), 512, 0, stream>>>(P, Vt, x, nullptr,
      2048, 1024, 2048, 4194304LL, 2097152LL, 2097152LL, 0LL, 1.0f);

  // 7) xt = x^T per batch; reshape(x^T) is then a plain [2048,1024] row-major matrix
  tr_bf16_k<<<dim3(32,64,4), dim3(32,8), 0, stream>>>(x, xt, 2097152LL, 2097152LL);

  // 8) out = reshape(x^T) @ Wo + bo  (f32 out)
  gemm8_k<0><<<dim3(4,8,4), 512, 0, stream>>>(xt, Wt + 3145728LL, (float*)d_out,
      biasb + 3072, 2048, 1024, 1024, 2097152LL, 0LL, 2097152LL, 0LL, 1.0f);
}

// Round 3
// 239.547 us; speedup vs baseline: 1.2990x; 1.1670x over previous
//
#include <hip/hip_runtime.h>
#include <hip/hip_bf16.h>
#include <stdint.h>

typedef __attribute__((ext_vector_type(8))) short short8;
typedef __attribute__((ext_vector_type(4))) float f32x4;
typedef const __attribute__((address_space(1))) uint32_t* gas1_t;
typedef __attribute__((address_space(3))) uint32_t* las3_t;

__device__ __forceinline__ short f2bf(float f) {
  uint32_t u = __builtin_bit_cast(uint32_t, f);
  u += 0x7fffu + ((u >> 16) & 1u);
  return (short)(u >> 16);
}
__device__ __forceinline__ float bf2f(short s) {
  return __builtin_bit_cast(float, ((uint32_t)(uint16_t)s) << 16);
}

// ---- convert q,k,v f32 -> bf16 (z selects tensor) ----
__global__ __launch_bounds__(256) void cvt_qkv_k(const float* __restrict__ q,
    const float* __restrict__ k, const float* __restrict__ v,
    short* __restrict__ dst) {
  const long long n = 8388608LL;
  const float* src = (blockIdx.z == 0) ? q : (blockIdx.z == 1) ? k : v;
  long long i = ((long long)blockIdx.x * 256 + threadIdx.x) * 8;
  float4 a = *(const float4*)(src + i);
  float4 b = *(const float4*)(src + i + 4);
  short8 o;
  o[0]=f2bf(a.x); o[1]=f2bf(a.y); o[2]=f2bf(a.z); o[3]=f2bf(a.w);
  o[4]=f2bf(b.x); o[5]=f2bf(b.y); o[6]=f2bf(b.z); o[7]=f2bf(b.w);
  *(short8*)(dst + (long long)blockIdx.z * n + i) = o;
}

// ---- gather the 4 bias vectors into one contiguous buffer ----
__global__ __launch_bounds__(256) void bias_gather_k(const float* b0, const float* b1,
    const float* b2, const float* b3, float* __restrict__ dst) {
  int i = blockIdx.x * 256 + threadIdx.x;
  if (i >= 4096) return;
  int z = i >> 10, j = i & 1023;
  const float* s = (z==0)?b0:(z==1)?b1:(z==2)?b2:b3;
  dst[i] = s[j];
}

// ---- weights: W[K=1024,N=1024] f32 -> Wt[N,K] bf16 (z selects weight) ----
__global__ __launch_bounds__(256) void wt_cvt_k(const float* w0, const float* w1,
    const float* w2, const float* w3, short* __restrict__ dst) {
  __shared__ float t[32][33];
  const float* W = (blockIdx.z==0)?w0:(blockIdx.z==1)?w1:(blockIdx.z==2)?w2:w3;
  short* D = dst + (long long)blockIdx.z * 1048576LL;
  int n0 = blockIdx.x * 32, k0 = blockIdx.y * 32;
  int tx = threadIdx.x, ty = threadIdx.y;
  #pragma unroll
  for (int i = 0; i < 4; ++i)
    t[ty + 8*i][tx] = W[(long long)(k0 + ty + 8*i) * 1024 + n0 + tx];
  __syncthreads();
  #pragma unroll
  for (int i = 0; i < 4; ++i)
    D[(long long)(n0 + ty + 8*i) * 1024 + k0 + tx] = f2bf(t[tx][ty + 8*i]);
}

// ---- bf16 transpose [2048,1024] -> [1024,2048], batched over z ----
__global__ __launch_bounds__(256) void tr_bf16_k(const short* __restrict__ in,
    short* __restrict__ out, long long sIn, long long sOut) {
  __shared__ short t[32][33];
  in  += (long long)blockIdx.z * sIn;
  out += (long long)blockIdx.z * sOut;
  int c0 = blockIdx.x * 32, r0 = blockIdx.y * 32;
  int tx = threadIdx.x, ty = threadIdx.y;
  #pragma unroll
  for (int i = 0; i < 4; ++i)
    t[ty + 8*i][tx] = in[(long long)(r0 + ty + 8*i) * 1024 + c0 + tx];
  __syncthreads();
  #pragma unroll
  for (int i = 0; i < 4; ++i)
    out[(long long)(c0 + ty + 8*i) * 2048 + r0 + tx] = t[tx][ty + 8*i];
}

// ---- in-place row softmax on bf16 [rows,2048] ----
__global__ __launch_bounds__(256) void softmax_bf_k(short* __restrict__ SP) {
  short* sp = SP + (long long)blockIdx.x * 2048;
  const int t = threadIdx.x;
  short8 sv = *(const short8*)(sp + t*8);
  float v[8];
  #pragma unroll
  for (int j = 0; j < 8; ++j) v[j] = bf2f(sv[j]);
  float m = v[0];
  #pragma unroll
  for (int j = 1; j < 8; ++j) m = fmaxf(m, v[j]);
  #pragma unroll
  for (int off = 32; off > 0; off >>= 1) m = fmaxf(m, __shfl_down(m, off, 64));
  __shared__ float rmax[4], rsum[4];
  int wv = t >> 6, ln = t & 63;
  if (ln == 0) rmax[wv] = m;
  __syncthreads();
  m = fmaxf(fmaxf(rmax[0], rmax[1]), fmaxf(rmax[2], rmax[3]));
  float e[8], sum = 0.f;
  #pragma unroll
  for (int j = 0; j < 8; ++j) { e[j] = exp2f((v[j] - m) * 1.44269504f); sum += e[j]; }
  #pragma unroll
  for (int off = 32; off > 0; off >>= 1) sum += __shfl_down(sum, off, 64);
  if (ln == 0) rsum[wv] = sum;
  __syncthreads();
  float inv = 1.0f / (rsum[0] + rsum[1] + rsum[2] + rsum[3]);
  short8 o;
  #pragma unroll
  for (int j = 0; j < 8; ++j) o[j] = f2bf(e[j] * inv);
  *(short8*)(sp + t*8) = o;
}

#define MFMA16(d, a_, b_) d = __builtin_amdgcn_mfma_f32_16x16x32_bf16(a_, b_, d, 0, 0, 0)
#define LGKM0 do { asm volatile("s_waitcnt lgkmcnt(0)" ::: "memory"); \
                   __builtin_amdgcn_sched_barrier(0); } while (0)
// flattened 1-D grid + bijective XCD-chunked swizzle (nwg % 8 == 0 at all call sites)
#define XCD_DECODE(gxs_, gys_) \
  const int nwg = (int)gridDim.x; \
  const int wg = ((int)blockIdx.x & 7) * (nwg >> 3) + ((int)blockIdx.x >> 3); \
  const int bxi = wg & ((1 << (gxs_)) - 1); \
  const int byi = (wg >> (gxs_)) & ((1 << (gys_)) - 1); \
  const int z = wg >> ((gxs_) + (gys_));

// ============================================================================
// 256x256 8-phase GEMM (proven R1 template + XCD swizzle). BK=64, 8 waves.
// ============================================================================
template<int OUT_BF16>
__global__ __launch_bounds__(512, 2) void gemm8_k(const short* __restrict__ A,
    const short* __restrict__ Bt, void* __restrict__ Cv,
    const float* __restrict__ bias,
    int M, int N, int K, long long sA, long long sB, long long sC,
    long long sBias, float scale, int gxs, int gys)
{
  __shared__ __align__(16) short lds[2][2][256*64];
  XCD_DECODE(gxs, gys);
  A  += (long long)z * sA;
  Bt += (long long)z * sB;
  const int bm = byi * 256;
  const int bn = bxi * 256;
  const int tid  = threadIdx.x;
  const int w    = tid >> 6, lane = tid & 63;
  const int wr   = w >> 2,   wc   = w & 3;
  const int lr   = lane & 15, lk  = lane >> 4;

  const int rsw0 = ((lk    ) ^ (lr & 7)) * 8;
  const int rsw1 = ((lk + 4) ^ (lr & 7)) * 8;
  const int srow = w * 8 + (lane >> 3);
  const int swc  = ((lane & 7) ^ ((lane >> 3) & 7)) * 8;
  const short* gA[4]; const short* gB[4];
  #pragma unroll
  for (int i = 0; i < 4; ++i) {
    gA[i] = A  + (long long)(bm + i*64 + srow) * K + swc;
    gB[i] = Bt + (long long)(bn + i*64 + srow) * K + swc;
  }

  #define STG(buf, ab, i, kt) \
    __builtin_amdgcn_global_load_lds((gas1_t)(((ab) ? gB : gA)[i] + (long long)(kt)*64), \
        (las3_t)&lds[buf][ab][(i)*4096 + w*512], 16, 0, 0)
  #define RDA(buf, mi, ks) (*(const short8*)&lds[buf][0][(wr*128 + (mi)*16 + lr)*64 + ((ks) ? rsw1 : rsw0)])
  #define RDB(buf, ni, ks) (*(const short8*)&lds[buf][1][(wc*64  + (ni)*16 + lr)*64 + ((ks) ? rsw1 : rsw0)])

  f32x4 acc[8][4] = {};
  const int nt = K >> 6;

  #pragma unroll
  for (int i = 0; i < 4; ++i) STG(0, 0, i, 0);
  #pragma unroll
  for (int i = 0; i < 4; ++i) STG(0, 1, i, 0);
  STG(1, 0, 0, 1); STG(1, 0, 2, 1);
  STG(1, 1, 0, 1); STG(1, 1, 1, 1);
  STG(1, 1, 2, 1); STG(1, 1, 3, 1);
  asm volatile("s_waitcnt vmcnt(6)" ::: "memory");
  __builtin_amdgcn_s_barrier();

  for (int g = 0; g < nt; ++g) {
    const int b = g & 1, nb = b ^ 1;
    short8 aR[4][2], bR[4][2];
    // phase 1
    #pragma unroll
    for (int mi = 0; mi < 4; ++mi) { aR[mi][0] = RDA(b, mi, 0); aR[mi][1] = RDA(b, mi, 1); }
    #pragma unroll
    for (int ni = 0; ni < 2; ++ni) { bR[ni][0] = RDB(b, ni, 0); bR[ni][1] = RDB(b, ni, 1); }
    if (g + 1 < nt) { STG(nb, 0, 1, g+1); STG(nb, 0, 3, g+1); }
    __builtin_amdgcn_s_barrier();
    LGKM0;
    __builtin_amdgcn_s_setprio(1);
    #pragma unroll
    for (int mi = 0; mi < 4; ++mi)
      #pragma unroll
      for (int ni = 0; ni < 2; ++ni) {
        MFMA16(acc[mi][ni], aR[mi][0], bR[ni][0]);
        MFMA16(acc[mi][ni], aR[mi][1], bR[ni][1]);
      }
    __builtin_amdgcn_s_setprio(0);
    __builtin_amdgcn_s_barrier();
    // phase 2
    #pragma unroll
    for (int ni = 2; ni < 4; ++ni) { bR[ni][0] = RDB(b, ni, 0); bR[ni][1] = RDB(b, ni, 1); }
    if (g + 2 < nt) { STG(b, 0, 0, g+2); STG(b, 0, 2, g+2); }
    __builtin_amdgcn_s_barrier();
    LGKM0;
    __builtin_amdgcn_s_setprio(1);
    #pragma unroll
    for (int mi = 0; mi < 4; ++mi)
      #pragma unroll
      for (int ni = 2; ni < 4; ++ni) {
        MFMA16(acc[mi][ni], aR[mi][0], bR[ni][0]);
        MFMA16(acc[mi][ni], aR[mi][1], bR[ni][1]);
      }
    __builtin_amdgcn_s_setprio(0);
    __builtin_amdgcn_s_barrier();
    // phase 3
    #pragma unroll
    for (int mi = 0; mi < 4; ++mi) { aR[mi][0] = RDA(b, mi+4, 0); aR[mi][1] = RDA(b, mi+4, 1); }
    if (g + 2 < nt) { STG(b, 1, 0, g+2); STG(b, 1, 1, g+2); }
    __builtin_amdgcn_s_barrier();
    LGKM0;
    __builtin_amdgcn_s_setprio(1);
    #pragma unroll
    for (int mi = 0; mi < 4; ++mi)
      #pragma unroll
      for (int ni = 0; ni < 2; ++ni) {
        MFMA16(acc[mi+4][ni], aR[mi][0], bR[ni][0]);
        MFMA16(acc[mi+4][ni], aR[mi][1], bR[ni][1]);
      }
    __builtin_amdgcn_s_setprio(0);
    __builtin_amdgcn_s_barrier();
    // phase 4
    if (g + 2 < nt) { STG(b, 1, 2, g+2); STG(b, 1, 3, g+2); }
    __builtin_amdgcn_s_setprio(1);
    #pragma unroll
    for (int mi = 0; mi < 4; ++mi)
      #pragma unroll
      for (int ni = 2; ni < 4; ++ni) {
        MFMA16(acc[mi+4][ni], aR[mi][0], bR[ni][0]);
        MFMA16(acc[mi+4][ni], aR[mi][1], bR[ni][1]);
      }
    __builtin_amdgcn_s_setprio(0);
    if (g + 1 < nt) {
      if (g + 2 < nt) asm volatile("s_waitcnt vmcnt(6)" ::: "memory");
      else            asm volatile("s_waitcnt vmcnt(0)" ::: "memory");
    }
    __builtin_amdgcn_s_barrier();
  }

  const float* bz = bias ? (bias + (long long)z * sBias) : nullptr;
  #pragma unroll
  for (int mi = 0; mi < 8; ++mi) {
    const int row = bm + wr*128 + mi*16 + lk*4;
    #pragma unroll
    for (int ni = 0; ni < 4; ++ni) {
      const int col = bn + wc*64 + ni*16 + lr;
      const float bval = bz ? bz[col] : 0.f;
      #pragma unroll
      for (int r = 0; r < 4; ++r) {
        float val = acc[mi][ni][r] * scale + bval;
        if (OUT_BF16)
          ((short*)Cv)[(long long)z*sC + (long long)(row + r) * N + col] = f2bf(val);
        else
          ((float*)Cv)[(long long)z*sC + (long long)(row + r) * N + col] = val;
      }
    }
  }
  #undef STG
  #undef RDA
  #undef RDB
}

// ============================================================================
// 256x128 2-phase GEMM. BM=256, BN=128, BK=64, 8 waves (2M x 4N), per-wave
// 128x32 out (acc[8][2]). Each phase = 16 MFMA (fat cluster preserved).
// FIFO-verified counted vmcnt: invariant at tile start O=[A1(g),A3(g)];
// P1 stages A0,A2,B0,B1(g+1), vmcnt(4) drains A1,A3(g) before P2 reads
// regions 1,3; P2 stages A1,A3(g+1), vmcnt(2) drains tile-(g+1) P1 deps.
// ============================================================================
template<int OUT_BF16>
__global__ __launch_bounds__(512, 2) void gemm4_k(const short* __restrict__ A,
    const short* __restrict__ Bt, void* __restrict__ Cv,
    const float* __restrict__ bias,
    int M, int N, int K, long long sA, long long sB, long long sC,
    long long sBias, float scale, int gxs, int gys)
{
  __shared__ __align__(16) short lds[2][24576];  // A: [0,16384) B: [16384,24576)
  XCD_DECODE(gxs, gys);
  A  += (long long)z * sA;
  Bt += (long long)z * sB;
  const int bm = byi * 256;
  const int bn = bxi * 128;
  const int tid  = threadIdx.x;
  const int w    = tid >> 6, lane = tid & 63;
  const int wr   = w >> 2,   wc   = w & 3;
  const int lr   = lane & 15, lk  = lane >> 4;

  const int rsw0 = ((lk    ) ^ (lr & 7)) * 8;
  const int rsw1 = ((lk + 4) ^ (lr & 7)) * 8;
  const int srow = w * 8 + (lane >> 3);
  const int swc  = ((lane & 7) ^ ((lane >> 3) & 7)) * 8;
  const short* gA[4]; const short* gB[2];
  #pragma unroll
  for (int i = 0; i < 4; ++i)
    gA[i] = A + (long long)(bm + i*64 + srow) * K + swc;
  #pragma unroll
  for (int i = 0; i < 2; ++i)
    gB[i] = Bt + (long long)(bn + i*64 + srow) * K + swc;

  #define STGA(buf, i, kt) \
    __builtin_amdgcn_global_load_lds((gas1_t)(gA[i] + (long long)(kt)*64), \
        (las3_t)&lds[buf][(i)*4096 + w*512], 16, 0, 0)
  #define STGB(buf, i, kt) \
    __builtin_amdgcn_global_load_lds((gas1_t)(gB[i] + (long long)(kt)*64), \
        (las3_t)&lds[buf][16384 + (i)*4096 + w*512], 16, 0, 0)
  #define RDA4(buf, mi, ks) (*(const short8*)&lds[buf][(wr*128 + (mi)*16 + lr)*64 + ((ks) ? rsw1 : rsw0)])
  #define RDB4(buf, ni, ks) (*(const short8*)&lds[buf][16384 + (wc*32 + (ni)*16 + lr)*64 + ((ks) ? rsw1 : rsw0)])

  f32x4 acc[8][2] = {};
  const int nt = K >> 6;

  // prologue: tile0 = A0,A2,B0,B1,A1,A3; drain first 4 -> O=[A1(0),A3(0)]
  STGA(0, 0, 0); STGA(0, 2, 0); STGB(0, 0, 0); STGB(0, 1, 0);
  STGA(0, 1, 0); STGA(0, 3, 0);
  asm volatile("s_waitcnt vmcnt(2)" ::: "memory");
  __builtin_amdgcn_s_barrier();

  for (int g = 0; g < nt; ++g) {
    const int b = g & 1, nb = b ^ 1;
    short8 aR[4][2], bR[2][2];
    // ---- P1: mi0-3 (A regions 0,2) x ni0-1 ----
    #pragma unroll
    for (int mi = 0; mi < 4; ++mi) { aR[mi][0] = RDA4(b, mi, 0); aR[mi][1] = RDA4(b, mi, 1); }
    #pragma unroll
    for (int ni = 0; ni < 2; ++ni) { bR[ni][0] = RDB4(b, ni, 0); bR[ni][1] = RDB4(b, ni, 1); }
    if (g + 1 < nt) { STGA(nb, 0, g+1); STGA(nb, 2, g+1); STGB(nb, 0, g+1); STGB(nb, 1, g+1); }
    __builtin_amdgcn_s_barrier();
    LGKM0;
    __builtin_amdgcn_s_setprio(1);
    #pragma unroll
    for (int mi = 0; mi < 4; ++mi)
      #pragma unroll
      for (int ni = 0; ni < 2; ++ni) {
        MFMA16(acc[mi][ni], aR[mi][0], bR[ni][0]);
        MFMA16(acc[mi][ni], aR[mi][1], bR[ni][1]);
      }
    __builtin_amdgcn_s_setprio(0);
    if (g + 1 < nt) asm volatile("s_waitcnt vmcnt(4)" ::: "memory");
    else            asm volatile("s_waitcnt vmcnt(0)" ::: "memory");
    __builtin_amdgcn_s_barrier();
    // ---- P2: mi4-7 (A regions 1,3) x ni0-1 ----
    #pragma unroll
    for (int mi = 0; mi < 4; ++mi) { aR[mi][0] = RDA4(b, mi+4, 0); aR[mi][1] = RDA4(b, mi+4, 1); }
    if (g + 1 < nt) { STGA(nb, 1, g+1); STGA(nb, 3, g+1); }
    __builtin_amdgcn_s_barrier();
    LGKM0;
    __builtin_amdgcn_s_setprio(1);
    #pragma unroll
    for (int mi = 0; mi < 4; ++mi)
      #pragma unroll
      for (int ni = 0; ni < 2; ++ni) {
        MFMA16(acc[mi+4][ni], aR[mi][0], bR[ni][0]);
        MFMA16(acc[mi+4][ni], aR[mi][1], bR[ni][1]);
      }
    __builtin_amdgcn_s_setprio(0);
    if (g + 1 < nt) asm volatile("s_waitcnt vmcnt(2)" ::: "memory");
    __builtin_amdgcn_s_barrier();
  }

  const float* bz = bias ? (bias + (long long)z * sBias) : nullptr;
  #pragma unroll
  for (int mi = 0; mi < 8; ++mi) {
    const int row = bm + wr*128 + mi*16 + lk*4;
    #pragma unroll
    for (int ni = 0; ni < 2; ++ni) {
      const int col = bn + wc*32 + ni*16 + lr;
      const float bval = bz ? bz[col] : 0.f;
      #pragma unroll
      for (int r = 0; r < 4; ++r) {
        float val = acc[mi][ni][r] * scale + bval;
        if (OUT_BF16)
          ((short*)Cv)[(long long)z*sC + (long long)(row + r) * N + col] = f2bf(val);
        else
          ((float*)Cv)[(long long)z*sC + (long long)(row + r) * N + col] = val;
      }
    }
  }
  #undef STGA
  #undef STGB
  #undef RDA4
  #undef RDB4
}

extern "C" void kernel_launch(void* const* d_in, const int* in_sizes, int n_in,
                              void* d_out, int out_size, void* d_ws, size_t ws_size,
                              hipStream_t stream) {
  const float* q  = (const float*)d_in[0];
  const float* k  = (const float*)d_in[1];
  const float* v  = (const float*)d_in[2];
  const float* Wq = (const float*)d_in[4];
  const float* bq = (const float*)d_in[5];
  const float* Wk = (const float*)d_in[6];
  const float* bk = (const float*)d_in[7];
  const float* Wv = (const float*)d_in[8];
  const float* bv = (const float*)d_in[9];
  const float* Wo = (const float*)d_in[10];
  const float* bo = (const float*)d_in[11];

  // ws layout (bytes), peak ~142.6 MB:
  char* w = (char*)d_ws;
  short* Wt     = (short*)(w);                  // [4][1024][1024] bf16      8,388,608
  float* biasb  = (float*)(w + 8388608);        // [4][1024] f32                16,384
  short* QKV    = (short*)(w + 8404992);        // [3][4,2048,1024] bf16    50,331,648
  short* qkvbf  = (short*)(w + 58736640);       // bf16 inputs (die post-proj) 50,331,648
  short* P      = (short*)(w + 58736640);       // scores/P bf16 [4,2048,2048] 33,554,432 (reuses qkvbf)
  short* x      = (short*)(w + 92291072);       // [4,2048,1024] bf16       16,777,216
  short* Vt     = (short*)(w + 109068288);      // [4,1024,2048] bf16       16,777,216
  short* xt     = (short*)(w + 125845504);      // [4,1024,2048] bf16       16,777,216

  short* Qp = QKV;
  short* Kp = QKV + 8388608LL;
  short* Vp = QKV + 16777216LL;

  // 1) convert inputs + weights, gather biases
  cvt_qkv_k<<<dim3(4096,1,3), 256, 0, stream>>>(q, k, v, qkvbf);
  bias_gather_k<<<dim3(16), 256, 0, stream>>>(bq, bk, bv, bo, biasb);
  wt_cvt_k<<<dim3(32,32,4), dim3(32,8), 0, stream>>>(Wq, Wk, Wv, Wo, Wt);

  // 2) projections: [8192,1024] = qkv @ W + b  (BN=128: 768 blocks = 3 rounds)
  gemm4_k<1><<<768, 512, 0, stream>>>(qkvbf, Wt, QKV, biasb,
      8192, 1024, 1024, 8388608LL, 1048576LL, 8388608LL, 1024LL, 1.0f, 3, 5);

  // 3) V^T per batch
  tr_bf16_k<<<dim3(32,64,4), dim3(32,8), 0, stream>>>(Vp, Vt, 2097152LL, 2097152LL);

  // 4) scores = Q @ K^T / 32 -> bf16 (256 blocks = 1 round)
  gemm8_k<1><<<256, 512, 0, stream>>>(Qp, Kp, P, nullptr,
      2048, 2048, 1024, 2097152LL, 2097152LL, 4194304LL, 0LL, 0.03125f, 3, 3);

  // 5) P = softmax_rows(P) in place
  softmax_bf_k<<<dim3(8192), 256, 0, stream>>>(P);

  // 6) x = P @ V  (BN=128: 256 blocks = 1 round)
  gemm4_k<1><<<256, 512, 0, stream>>>(P, Vt, x, nullptr,
      2048, 1024, 2048, 4194304LL, 2097152LL, 2097152LL, 0LL, 1.0f, 3, 3);

  // 7) xt = x^T per batch
  tr_bf16_k<<<dim3(32,64,4), dim3(32,8), 0, stream>>>(x, xt, 2097152LL, 2097152LL);

  // 8) out = reshape(x^T) @ Wo + bo  (BN=128: 256 blocks = 1 round)
  gemm4_k<0><<<256, 512, 0, stream>>>(xt, Wt + 3145728LL, (float*)d_out,
      biasb + 3072, 2048, 1024, 1024, 2097152LL, 0LL, 2097152LL, 0LL, 1.0f, 3, 3);
}

// Round 4
// 221.896 us; speedup vs baseline: 1.4023x; 1.0795x over previous
//
#include <hip/hip_runtime.h>
#include <hip/hip_bf16.h>
#include <stdint.h>

typedef __attribute__((ext_vector_type(8))) short short8;
typedef __attribute__((ext_vector_type(4))) float f32x4;
typedef const __attribute__((address_space(1))) uint32_t* gas1_t;
typedef __attribute__((address_space(3))) uint32_t* las3_t;

__device__ __forceinline__ short f2bf(float f) {
  uint32_t u = __builtin_bit_cast(uint32_t, f);
  u += 0x7fffu + ((u >> 16) & 1u);
  return (short)(u >> 16);
}
__device__ __forceinline__ float bf2f(short s) {
  return __builtin_bit_cast(float, ((uint32_t)(uint16_t)s) << 16);
}

// ---- convert q,k,v f32 -> bf16 (z selects tensor) ----
__global__ __launch_bounds__(256) void cvt_qkv_k(const float* __restrict__ q,
    const float* __restrict__ k, const float* __restrict__ v,
    short* __restrict__ dst) {
  const long long n = 8388608LL;
  const float* src = (blockIdx.z == 0) ? q : (blockIdx.z == 1) ? k : v;
  long long i = ((long long)blockIdx.x * 256 + threadIdx.x) * 8;
  float4 a = *(const float4*)(src + i);
  float4 b = *(const float4*)(src + i + 4);
  short8 o;
  o[0]=f2bf(a.x); o[1]=f2bf(a.y); o[2]=f2bf(a.z); o[3]=f2bf(a.w);
  o[4]=f2bf(b.x); o[5]=f2bf(b.y); o[6]=f2bf(b.z); o[7]=f2bf(b.w);
  *(short8*)(dst + (long long)blockIdx.z * n + i) = o;
}

// ---- gather the 4 bias vectors into one contiguous buffer ----
__global__ __launch_bounds__(256) void bias_gather_k(const float* b0, const float* b1,
    const float* b2, const float* b3, float* __restrict__ dst) {
  int i = blockIdx.x * 256 + threadIdx.x;
  if (i >= 4096) return;
  int z = i >> 10, j = i & 1023;
  const float* s = (z==0)?b0:(z==1)?b1:(z==2)?b2:b3;
  dst[i] = s[j];
}

// ---- weights: W[K=1024,N=1024] f32 -> Wt[N,K] bf16 (z selects weight) ----
__global__ __launch_bounds__(256) void wt_cvt_k(const float* w0, const float* w1,
    const float* w2, const float* w3, short* __restrict__ dst) {
  __shared__ float t[32][33];
  const float* W = (blockIdx.z==0)?w0:(blockIdx.z==1)?w1:(blockIdx.z==2)?w2:w3;
  short* D = dst + (long long)blockIdx.z * 1048576LL;
  int n0 = blockIdx.x * 32, k0 = blockIdx.y * 32;
  int tx = threadIdx.x, ty = threadIdx.y;
  #pragma unroll
  for (int i = 0; i < 4; ++i)
    t[ty + 8*i][tx] = W[(long long)(k0 + ty + 8*i) * 1024 + n0 + tx];
  __syncthreads();
  #pragma unroll
  for (int i = 0; i < 4; ++i)
    D[(long long)(n0 + ty + 8*i) * 1024 + k0 + tx] = f2bf(t[tx][ty + 8*i]);
}

// ---- in-place row softmax on bf16 [rows,2048] ----
__global__ __launch_bounds__(256) void softmax_bf_k(short* __restrict__ SP) {
  short* sp = SP + (long long)blockIdx.x * 2048;
  const int t = threadIdx.x;
  short8 sv = *(const short8*)(sp + t*8);
  float v[8];
  #pragma unroll
  for (int j = 0; j < 8; ++j) v[j] = bf2f(sv[j]);
  float m = v[0];
  #pragma unroll
  for (int j = 1; j < 8; ++j) m = fmaxf(m, v[j]);
  #pragma unroll
  for (int off = 32; off > 0; off >>= 1) m = fmaxf(m, __shfl_down(m, off, 64));
  __shared__ float rmax[4], rsum[4];
  int wv = t >> 6, ln = t & 63;
  if (ln == 0) rmax[wv] = m;
  __syncthreads();
  m = fmaxf(fmaxf(rmax[0], rmax[1]), fmaxf(rmax[2], rmax[3]));
  float e[8], sum = 0.f;
  #pragma unroll
  for (int j = 0; j < 8; ++j) { e[j] = exp2f((v[j] - m) * 1.44269504f); sum += e[j]; }
  #pragma unroll
  for (int off = 32; off > 0; off >>= 1) sum += __shfl_down(sum, off, 64);
  if (ln == 0) rsum[wv] = sum;
  __syncthreads();
  float inv = 1.0f / (rsum[0] + rsum[1] + rsum[2] + rsum[3]);
  short8 o;
  #pragma unroll
  for (int j = 0; j < 8; ++j) o[j] = f2bf(e[j] * inv);
  *(short8*)(sp + t*8) = o;
}

#define MFMA16(d, a_, b_) d = __builtin_amdgcn_mfma_f32_16x16x32_bf16(a_, b_, d, 0, 0, 0)
#define LGKM0 do { asm volatile("s_waitcnt lgkmcnt(0)" ::: "memory"); \
                   __builtin_amdgcn_sched_barrier(0); } while (0)
// flattened 1-D grid + bijective XCD-chunked swizzle (nwg % 8 == 0 at all call sites)
#define XCD_DECODE(gxs_, gys_) \
  const int nwg = (int)gridDim.x; \
  const int wg = ((int)blockIdx.x & 7) * (nwg >> 3) + ((int)blockIdx.x >> 3); \
  const int bxi = wg & ((1 << (gxs_)) - 1); \
  const int byi = (wg >> (gxs_)) & ((1 << (gys_)) - 1); \
  const int z = wg >> ((gxs_) + (gys_));

// ============================================================================
// 256x256 8-phase GEMM (proven R1 template + XCD swizzle). BK=64, 8 waves.
// ============================================================================
template<int OUT_BF16>
__global__ __launch_bounds__(512, 2) void gemm8_k(const short* __restrict__ A,
    const short* __restrict__ Bt, void* __restrict__ Cv,
    const float* __restrict__ bias,
    int M, int N, int K, long long sA, long long sB, long long sC,
    long long sBias, float scale, int gxs, int gys)
{
  __shared__ __align__(16) short lds[2][2][256*64];
  XCD_DECODE(gxs, gys);
  A  += (long long)z * sA;
  Bt += (long long)z * sB;
  const int bm = byi * 256;
  const int bn = bxi * 256;
  const int tid  = threadIdx.x;
  const int w    = tid >> 6, lane = tid & 63;
  const int wr   = w >> 2,   wc   = w & 3;
  const int lr   = lane & 15, lk  = lane >> 4;

  const int rsw0 = ((lk    ) ^ (lr & 7)) * 8;
  const int rsw1 = ((lk + 4) ^ (lr & 7)) * 8;
  const int srow = w * 8 + (lane >> 3);
  const int swc  = ((lane & 7) ^ ((lane >> 3) & 7)) * 8;
  const short* gA[4]; const short* gB[4];
  #pragma unroll
  for (int i = 0; i < 4; ++i) {
    gA[i] = A  + (long long)(bm + i*64 + srow) * K + swc;
    gB[i] = Bt + (long long)(bn + i*64 + srow) * K + swc;
  }

  #define STG(buf, ab, i, kt) \
    __builtin_amdgcn_global_load_lds((gas1_t)(((ab) ? gB : gA)[i] + (long long)(kt)*64), \
        (las3_t)&lds[buf][ab][(i)*4096 + w*512], 16, 0, 0)
  #define RDA(buf, mi, ks) (*(const short8*)&lds[buf][0][(wr*128 + (mi)*16 + lr)*64 + ((ks) ? rsw1 : rsw0)])
  #define RDB(buf, ni, ks) (*(const short8*)&lds[buf][1][(wc*64  + (ni)*16 + lr)*64 + ((ks) ? rsw1 : rsw0)])

  f32x4 acc[8][4] = {};
  const int nt = K >> 6;

  #pragma unroll
  for (int i = 0; i < 4; ++i) STG(0, 0, i, 0);
  #pragma unroll
  for (int i = 0; i < 4; ++i) STG(0, 1, i, 0);
  STG(1, 0, 0, 1); STG(1, 0, 2, 1);
  STG(1, 1, 0, 1); STG(1, 1, 1, 1);
  STG(1, 1, 2, 1); STG(1, 1, 3, 1);
  asm volatile("s_waitcnt vmcnt(6)" ::: "memory");
  __builtin_amdgcn_s_barrier();

  for (int g = 0; g < nt; ++g) {
    const int b = g & 1, nb = b ^ 1;
    short8 aR[4][2], bR[4][2];
    // phase 1
    #pragma unroll
    for (int mi = 0; mi < 4; ++mi) { aR[mi][0] = RDA(b, mi, 0); aR[mi][1] = RDA(b, mi, 1); }
    #pragma unroll
    for (int ni = 0; ni < 2; ++ni) { bR[ni][0] = RDB(b, ni, 0); bR[ni][1] = RDB(b, ni, 1); }
    if (g + 1 < nt) { STG(nb, 0, 1, g+1); STG(nb, 0, 3, g+1); }
    __builtin_amdgcn_s_barrier();
    LGKM0;
    __builtin_amdgcn_s_setprio(1);
    #pragma unroll
    for (int mi = 0; mi < 4; ++mi)
      #pragma unroll
      for (int ni = 0; ni < 2; ++ni) {
        MFMA16(acc[mi][ni], aR[mi][0], bR[ni][0]);
        MFMA16(acc[mi][ni], aR[mi][1], bR[ni][1]);
      }
    __builtin_amdgcn_s_setprio(0);
    __builtin_amdgcn_s_barrier();
    // phase 2
    #pragma unroll
    for (int ni = 2; ni < 4; ++ni) { bR[ni][0] = RDB(b, ni, 0); bR[ni][1] = RDB(b, ni, 1); }
    if (g + 2 < nt) { STG(b, 0, 0, g+2); STG(b, 0, 2, g+2); }
    __builtin_amdgcn_s_barrier();
    LGKM0;
    __builtin_amdgcn_s_setprio(1);
    #pragma unroll
    for (int mi = 0; mi < 4; ++mi)
      #pragma unroll
      for (int ni = 2; ni < 4; ++ni) {
        MFMA16(acc[mi][ni], aR[mi][0], bR[ni][0]);
        MFMA16(acc[mi][ni], aR[mi][1], bR[ni][1]);
      }
    __builtin_amdgcn_s_setprio(0);
    __builtin_amdgcn_s_barrier();
    // phase 3
    #pragma unroll
    for (int mi = 0; mi < 4; ++mi) { aR[mi][0] = RDA(b, mi+4, 0); aR[mi][1] = RDA(b, mi+4, 1); }
    if (g + 2 < nt) { STG(b, 1, 0, g+2); STG(b, 1, 1, g+2); }
    __builtin_amdgcn_s_barrier();
    LGKM0;
    __builtin_amdgcn_s_setprio(1);
    #pragma unroll
    for (int mi = 0; mi < 4; ++mi)
      #pragma unroll
      for (int ni = 0; ni < 2; ++ni) {
        MFMA16(acc[mi+4][ni], aR[mi][0], bR[ni][0]);
        MFMA16(acc[mi+4][ni], aR[mi][1], bR[ni][1]);
      }
    __builtin_amdgcn_s_setprio(0);
    __builtin_amdgcn_s_barrier();
    // phase 4
    if (g + 2 < nt) { STG(b, 1, 2, g+2); STG(b, 1, 3, g+2); }
    __builtin_amdgcn_s_setprio(1);
    #pragma unroll
    for (int mi = 0; mi < 4; ++mi)
      #pragma unroll
      for (int ni = 2; ni < 4; ++ni) {
        MFMA16(acc[mi+4][ni], aR[mi][0], bR[ni][0]);
        MFMA16(acc[mi+4][ni], aR[mi][1], bR[ni][1]);
      }
    __builtin_amdgcn_s_setprio(0);
    if (g + 1 < nt) {
      if (g + 2 < nt) asm volatile("s_waitcnt vmcnt(6)" ::: "memory");
      else            asm volatile("s_waitcnt vmcnt(0)" ::: "memory");
    }
    __builtin_amdgcn_s_barrier();
  }

  const float* bz = bias ? (bias + (long long)z * sBias) : nullptr;
  #pragma unroll
  for (int mi = 0; mi < 8; ++mi) {
    const int row = bm + wr*128 + mi*16 + lk*4;
    #pragma unroll
    for (int ni = 0; ni < 4; ++ni) {
      const int col = bn + wc*64 + ni*16 + lr;
      const float bval = bz ? bz[col] : 0.f;
      #pragma unroll
      for (int r = 0; r < 4; ++r) {
        float val = acc[mi][ni][r] * scale + bval;
        if (OUT_BF16)
          ((short*)Cv)[(long long)z*sC + (long long)(row + r) * N + col] = f2bf(val);
        else
          ((float*)Cv)[(long long)z*sC + (long long)(row + r) * N + col] = val;
      }
    }
  }
  #undef STG
  #undef RDA
  #undef RDB
}

// ============================================================================
// 256x128 GEMM, 3-buffer ring, stage-distance 2, ONE barrier per K-tile.
// BM=256, BN=128, BK=64, 8 waves (2M x 4N), per-wave 128x32, acc[8][2].
// Hazards: STG for tile g+2 -> buf (g+2)%3, last read at tile g-1 (>=2
// barriers back). vmcnt(6) at tile end = all 6 tile-(g+1) loads (per wave)
// landed; barrier makes that hold across waves. Prefetch window ~1.5 tiles.
// lda/ldb/ldc strides; BIAS_ROW: bias indexed by output row (for Wt-side A).
// ============================================================================
template<int OUT_BF16, int BIAS_ROW>
__global__ __launch_bounds__(512, 2) void gemm4_k(const short* __restrict__ A,
    const short* __restrict__ Bt, void* __restrict__ Cv,
    const float* __restrict__ bias,
    int K, int lda, int ldb, int ldc,
    long long sA, long long sB, long long sC, long long sBias,
    float scale, int gxs, int gys)
{
  __shared__ __align__(16) short lds[3][24576];  // per buf: A [0,16384) B [16384,24576)
  XCD_DECODE(gxs, gys);
  A  += (long long)z * sA;
  Bt += (long long)z * sB;
  const int bm = byi * 256;
  const int bn = bxi * 128;
  const int tid  = threadIdx.x;
  const int w    = tid >> 6, lane = tid & 63;
  const int wr   = w >> 2,   wc   = w & 3;
  const int lr   = lane & 15, lk  = lane >> 4;

  const int rsw0 = ((lk    ) ^ (lr & 7)) * 8;
  const int rsw1 = ((lk + 4) ^ (lr & 7)) * 8;
  const int srow = w * 8 + (lane >> 3);
  const int swc  = ((lane & 7) ^ ((lane >> 3) & 7)) * 8;
  const short* gA[4]; const short* gB[2];
  #pragma unroll
  for (int i = 0; i < 4; ++i)
    gA[i] = A + (long long)(bm + i*64 + srow) * lda + swc;
  #pragma unroll
  for (int i = 0; i < 2; ++i)
    gB[i] = Bt + (long long)(bn + i*64 + srow) * ldb + swc;

  #define STGA(buf, i, kt) \
    __builtin_amdgcn_global_load_lds((gas1_t)(gA[i] + (long long)(kt)*64), \
        (las3_t)&lds[buf][(i)*4096 + w*512], 16, 0, 0)
  #define STGB(buf, i, kt) \
    __builtin_amdgcn_global_load_lds((gas1_t)(gB[i] + (long long)(kt)*64), \
        (las3_t)&lds[buf][16384 + (i)*4096 + w*512], 16, 0, 0)
  #define RDA4(buf, mi, ks) (*(const short8*)&lds[buf][(wr*128 + (mi)*16 + lr)*64 + ((ks) ? rsw1 : rsw0)])
  #define RDB4(buf, ni, ks) (*(const short8*)&lds[buf][16384 + (wc*32 + (ni)*16 + lr)*64 + ((ks) ? rsw1 : rsw0)])

  f32x4 acc[8][2] = {};
  const int nt = K >> 6;

  // prologue: stage tile0 -> buf0, tile1 -> buf1; wait tile0 (keep 6 in flight)
  STGA(0, 0, 0); STGA(0, 2, 0); STGB(0, 0, 0);
  STGB(0, 1, 0); STGA(0, 1, 0); STGA(0, 3, 0);
  STGA(1, 0, 1); STGA(1, 2, 1); STGB(1, 0, 1);
  STGB(1, 1, 1); STGA(1, 1, 1); STGA(1, 3, 1);
  asm volatile("s_waitcnt vmcnt(6)" ::: "memory");
  __builtin_amdgcn_s_barrier();

  int b = 0, nb = 2;
  for (int g = 0; g < nt; ++g) {
    short8 aR[4][2], bR[2][2];
    // ---- half 1: A regions 0,2 (mi0-3) ----
    #pragma unroll
    for (int mi = 0; mi < 4; ++mi) { aR[mi][0] = RDA4(b, mi, 0); aR[mi][1] = RDA4(b, mi, 1); }
    #pragma unroll
    for (int ni = 0; ni < 2; ++ni) { bR[ni][0] = RDB4(b, ni, 0); bR[ni][1] = RDB4(b, ni, 1); }
    if (g + 2 < nt) { STGA(nb, 0, g+2); STGA(nb, 2, g+2); STGB(nb, 0, g+2); }
    LGKM0;
    __builtin_amdgcn_s_setprio(1);
    #pragma unroll
    for (int mi = 0; mi < 4; ++mi)
      #pragma unroll
      for (int ni = 0; ni < 2; ++ni) {
        MFMA16(acc[mi][ni], aR[mi][0], bR[ni][0]);
        MFMA16(acc[mi][ni], aR[mi][1], bR[ni][1]);
      }
    __builtin_amdgcn_s_setprio(0);
    // ---- half 2: A regions 1,3 (mi4-7) ----
    #pragma unroll
    for (int mi = 0; mi < 4; ++mi) { aR[mi][0] = RDA4(b, mi+4, 0); aR[mi][1] = RDA4(b, mi+4, 1); }
    if (g + 2 < nt) { STGB(nb, 1, g+2); STGA(nb, 1, g+2); STGA(nb, 3, g+2); }
    LGKM0;
    __builtin_amdgcn_s_setprio(1);
    #pragma unroll
    for (int mi = 0; mi < 4; ++mi)
      #pragma unroll
      for (int ni = 0; ni < 2; ++ni) {
        MFMA16(acc[mi+4][ni], aR[mi][0], bR[ni][0]);
        MFMA16(acc[mi+4][ni], aR[mi][1], bR[ni][1]);
      }
    __builtin_amdgcn_s_setprio(0);
    if (g + 2 < nt)      asm volatile("s_waitcnt vmcnt(6)" ::: "memory");
    else if (g + 1 < nt) asm volatile("s_waitcnt vmcnt(0)" ::: "memory");
    __builtin_amdgcn_s_barrier();
    b  = (b  == 2) ? 0 : b  + 1;
    nb = (nb == 2) ? 0 : nb + 1;
  }

  const float* bz = bias;
  #pragma unroll
  for (int mi = 0; mi < 8; ++mi) {
    const int row = bm + wr*128 + mi*16 + lk*4;
    #pragma unroll
    for (int ni = 0; ni < 2; ++ni) {
      const int col = bn + wc*32 + ni*16 + lr;
      const float bcol = (bz && !BIAS_ROW) ? bz[(long long)z*sBias + col] : 0.f;
      #pragma unroll
      for (int r = 0; r < 4; ++r) {
        float bval = BIAS_ROW ? bz[row + r] : bcol;
        float val = acc[mi][ni][r] * scale + bval;
        if (OUT_BF16)
          ((short*)Cv)[(long long)z*sC + (long long)(row + r) * ldc + col] = f2bf(val);
        else
          ((float*)Cv)[(long long)z*sC + (long long)(row + r) * ldc + col] = val;
      }
    }
  }
  #undef STGA
  #undef STGB
  #undef RDA4
  #undef RDB4
}

extern "C" void kernel_launch(void* const* d_in, const int* in_sizes, int n_in,
                              void* d_out, int out_size, void* d_ws, size_t ws_size,
                              hipStream_t stream) {
  const float* q  = (const float*)d_in[0];
  const float* k  = (const float*)d_in[1];
  const float* v  = (const float*)d_in[2];
  const float* Wq = (const float*)d_in[4];
  const float* bq = (const float*)d_in[5];
  const float* Wk = (const float*)d_in[6];
  const float* bk = (const float*)d_in[7];
  const float* Wv = (const float*)d_in[8];
  const float* bv = (const float*)d_in[9];
  const float* Wo = (const float*)d_in[10];
  const float* bo = (const float*)d_in[11];

  // ws layout (bytes), peak ~125.8 MB:
  char* w = (char*)d_ws;
  short* Wt     = (short*)(w);                  // [4][1024][1024] bf16 (W^T)   8,388,608
  float* biasb  = (float*)(w + 8388608);        // [4][1024] f32                   16,384
  short* QKV    = (short*)(w + 8404992);        // Q,K bf16 [2][4,2048,1024]   (V slot unused)
  short* qkvbf  = (short*)(w + 58736640);       // q,k,v bf16, dies after projections
  short* P      = (short*)(w + 58736640);       // scores/P bf16 [4,2048,2048] (reuses qkvbf)
  short* Vt     = (short*)(w + 92291072);       // [1024][8192] bf16 (d x (b,s)) 16,777,216
  short* xt     = (short*)(w + 109068288);      // [4][1024][2048] bf16          16,777,216

  short* Qp = QKV;
  short* Kp = QKV + 8388608LL;
  short* vbf = qkvbf + 16777216LL;

  // 1) convert inputs + weights, gather biases
  cvt_qkv_k<<<dim3(4096,1,3), 256, 0, stream>>>(q, k, v, qkvbf);
  bias_gather_k<<<dim3(16), 256, 0, stream>>>(bq, bk, bv, bo, biasb);
  wt_cvt_k<<<dim3(32,32,4), dim3(32,8), 0, stream>>>(Wq, Wk, Wv, Wo, Wt);

  // 2a) q,k projections: [8192,1024] = qkv[z] @ W[z] + b[z]  (512 blocks = 2 rounds)
  gemm4_k<1,0><<<512, 512, 0, stream>>>(qkvbf, Wt, QKV, biasb,
      1024, 1024, 1024, 1024, 8388608LL, 1048576LL, 8388608LL, 1024LL, 1.0f, 3, 5);

  // 2b) V projection, transposed output: Vt[d, bs] = Wv^T @ v_bf^T + bv[d]
  //     A = Wt_v [1024x1024], Bt = vbf [8192x1024], C ldc=8192, row-bias (256 blocks)
  gemm4_k<1,1><<<256, 512, 0, stream>>>(Wt + 2097152LL, vbf, Vt, biasb + 2048,
      1024, 1024, 1024, 8192, 0LL, 0LL, 0LL, 0LL, 1.0f, 6, 2);

  // 3) scores = Q @ K^T / 32 -> bf16 P (256 blocks = 1 round)
  gemm8_k<1><<<256, 512, 0, stream>>>(Qp, Kp, P, nullptr,
      2048, 2048, 1024, 2097152LL, 2097152LL, 4194304LL, 0LL, 0.03125f, 3, 3);

  // 4) P = softmax_rows(P) in place
  softmax_bf_k<<<dim3(8192), 256, 0, stream>>>(P);

  // 5) xt[d, q] = Vt[d,:] . P[q,:]  — PV with swapped operands writes the
  //    permuted layout directly (A = Vt + z*2048 cols, lda=8192) (256 blocks)
  gemm4_k<1,0><<<256, 512, 0, stream>>>(Vt, P, xt, nullptr,
      2048, 8192, 2048, 2048, 2048LL, 4194304LL, 2097152LL, 0LL, 1.0f, 4, 2);

  // 6) out = reshape(xt) @ Wo + bo; xt buffer reinterpreted [2048][1024] row-major
  gemm4_k<0,0><<<256, 512, 0, stream>>>(xt, Wt + 3145728LL, (float*)d_out,
      biasb + 3072, 1024, 1024, 1024, 1024, 2097152LL, 0LL, 2097152LL, 0LL, 1.0f, 3, 3);
}

// Round 5
// 210.442 us; speedup vs baseline: 1.4787x; 1.0544x over previous
//
#include <hip/hip_runtime.h>
#include <hip/hip_bf16.h>
#include <stdint.h>

typedef __attribute__((ext_vector_type(8))) short short8;
typedef __attribute__((ext_vector_type(4))) float f32x4;
typedef const __attribute__((address_space(1))) uint32_t* gas1_t;
typedef __attribute__((address_space(3))) uint32_t* las3_t;

__device__ __forceinline__ short f2bf(float f) {
  uint32_t u = __builtin_bit_cast(uint32_t, f);
  u += 0x7fffu + ((u >> 16) & 1u);
  return (short)(u >> 16);
}
__device__ __forceinline__ float bf2f(short s) {
  return __builtin_bit_cast(float, ((uint32_t)(uint16_t)s) << 16);
}

// ---- convert q,k,v f32 -> bf16 (z selects tensor) ----
__global__ __launch_bounds__(256) void cvt_qkv_k(const float* __restrict__ q,
    const float* __restrict__ k, const float* __restrict__ v,
    short* __restrict__ dst) {
  const long long n = 8388608LL;
  const float* src = (blockIdx.z == 0) ? q : (blockIdx.z == 1) ? k : v;
  long long i = ((long long)blockIdx.x * 256 + threadIdx.x) * 8;
  float4 a = *(const float4*)(src + i);
  float4 b = *(const float4*)(src + i + 4);
  short8 o;
  o[0]=f2bf(a.x); o[1]=f2bf(a.y); o[2]=f2bf(a.z); o[3]=f2bf(a.w);
  o[4]=f2bf(b.x); o[5]=f2bf(b.y); o[6]=f2bf(b.z); o[7]=f2bf(b.w);
  *(short8*)(dst + (long long)blockIdx.z * n + i) = o;
}

// ---- gather the 4 bias vectors into one contiguous buffer ----
__global__ __launch_bounds__(256) void bias_gather_k(const float* b0, const float* b1,
    const float* b2, const float* b3, float* __restrict__ dst) {
  int i = blockIdx.x * 256 + threadIdx.x;
  if (i >= 4096) return;
  int z = i >> 10, j = i & 1023;
  const float* s = (z==0)?b0:(z==1)?b1:(z==2)?b2:b3;
  dst[i] = s[j];
}

// ---- weights: W[K=1024,N=1024] f32 -> Wt[N,K] bf16 (z selects weight) ----
__global__ __launch_bounds__(256) void wt_cvt_k(const float* w0, const float* w1,
    const float* w2, const float* w3, short* __restrict__ dst) {
  __shared__ float t[32][33];
  const float* W = (blockIdx.z==0)?w0:(blockIdx.z==1)?w1:(blockIdx.z==2)?w2:w3;
  short* D = dst + (long long)blockIdx.z * 1048576LL;
  int n0 = blockIdx.x * 32, k0 = blockIdx.y * 32;
  int tx = threadIdx.x, ty = threadIdx.y;
  #pragma unroll
  for (int i = 0; i < 4; ++i)
    t[ty + 8*i][tx] = W[(long long)(k0 + ty + 8*i) * 1024 + n0 + tx];
  __syncthreads();
  #pragma unroll
  for (int i = 0; i < 4; ++i)
    D[(long long)(n0 + ty + 8*i) * 1024 + k0 + tx] = f2bf(t[tx][ty + 8*i]);
}

// ---- in-place row softmax on bf16 [rows,2048] ----
__global__ __launch_bounds__(256) void softmax_bf_k(short* __restrict__ SP) {
  short* sp = SP + (long long)blockIdx.x * 2048;
  const int t = threadIdx.x;
  short8 sv = *(const short8*)(sp + t*8);
  float v[8];
  #pragma unroll
  for (int j = 0; j < 8; ++j) v[j] = bf2f(sv[j]);
  float m = v[0];
  #pragma unroll
  for (int j = 1; j < 8; ++j) m = fmaxf(m, v[j]);
  #pragma unroll
  for (int off = 32; off > 0; off >>= 1) m = fmaxf(m, __shfl_down(m, off, 64));
  __shared__ float rmax[4], rsum[4];
  int wv = t >> 6, ln = t & 63;
  if (ln == 0) rmax[wv] = m;
  __syncthreads();
  m = fmaxf(fmaxf(rmax[0], rmax[1]), fmaxf(rmax[2], rmax[3]));
  float e[8], sum = 0.f;
  #pragma unroll
  for (int j = 0; j < 8; ++j) { e[j] = exp2f((v[j] - m) * 1.44269504f); sum += e[j]; }
  #pragma unroll
  for (int off = 32; off > 0; off >>= 1) sum += __shfl_down(sum, off, 64);
  if (ln == 0) rsum[wv] = sum;
  __syncthreads();
  float inv = 1.0f / (rsum[0] + rsum[1] + rsum[2] + rsum[3]);
  short8 o;
  #pragma unroll
  for (int j = 0; j < 8; ++j) o[j] = f2bf(e[j] * inv);
  *(short8*)(sp + t*8) = o;
}

#define MFMA16(d, a_, b_) d = __builtin_amdgcn_mfma_f32_16x16x32_bf16(a_, b_, d, 0, 0, 0)
#define LGKM0 do { asm volatile("s_waitcnt lgkmcnt(0)" ::: "memory"); \
                   __builtin_amdgcn_sched_barrier(0); } while (0)
// flattened 1-D grid + bijective XCD-chunked swizzle (nwg % 8 == 0 at all call sites)
#define XCD_DECODE(gxs_, gys_) \
  const int nwg = (int)gridDim.x; \
  const int wg = ((int)blockIdx.x & 7) * (nwg >> 3) + ((int)blockIdx.x >> 3); \
  const int bxi = wg & ((1 << (gxs_)) - 1); \
  const int byi = (wg >> (gxs_)) & ((1 << (gys_)) - 1); \
  const int z = wg >> ((gxs_) + (gys_));

// ============================================================================
// 256x256 8-phase GEMM (proven template + XCD swizzle). BK=64, 8 waves.
// ============================================================================
template<int OUT_BF16>
__global__ __launch_bounds__(512, 2) void gemm8_k(const short* __restrict__ A,
    const short* __restrict__ Bt, void* __restrict__ Cv,
    const float* __restrict__ bias,
    int M, int N, int K, long long sA, long long sB, long long sC,
    long long sBias, float scale, int gxs, int gys)
{
  __shared__ __align__(16) short lds[2][2][256*64];
  XCD_DECODE(gxs, gys);
  A  += (long long)z * sA;
  Bt += (long long)z * sB;
  const int bm = byi * 256;
  const int bn = bxi * 256;
  const int tid  = threadIdx.x;
  const int w    = tid >> 6, lane = tid & 63;
  const int wr   = w >> 2,   wc   = w & 3;
  const int lr   = lane & 15, lk  = lane >> 4;

  const int rsw0 = ((lk    ) ^ (lr & 7)) * 8;
  const int rsw1 = ((lk + 4) ^ (lr & 7)) * 8;
  const int srow = w * 8 + (lane >> 3);
  const int swc  = ((lane & 7) ^ ((lane >> 3) & 7)) * 8;
  const short* gA[4]; const short* gB[4];
  #pragma unroll
  for (int i = 0; i < 4; ++i) {
    gA[i] = A  + (long long)(bm + i*64 + srow) * K + swc;
    gB[i] = Bt + (long long)(bn + i*64 + srow) * K + swc;
  }

  #define STG(buf, ab, i, kt) \
    __builtin_amdgcn_global_load_lds((gas1_t)(((ab) ? gB : gA)[i] + (long long)(kt)*64), \
        (las3_t)&lds[buf][ab][(i)*4096 + w*512], 16, 0, 0)
  #define RDA(buf, mi, ks) (*(const short8*)&lds[buf][0][(wr*128 + (mi)*16 + lr)*64 + ((ks) ? rsw1 : rsw0)])
  #define RDB(buf, ni, ks) (*(const short8*)&lds[buf][1][(wc*64  + (ni)*16 + lr)*64 + ((ks) ? rsw1 : rsw0)])

  f32x4 acc[8][4] = {};
  const int nt = K >> 6;

  #pragma unroll
  for (int i = 0; i < 4; ++i) STG(0, 0, i, 0);
  #pragma unroll
  for (int i = 0; i < 4; ++i) STG(0, 1, i, 0);
  STG(1, 0, 0, 1); STG(1, 0, 2, 1);
  STG(1, 1, 0, 1); STG(1, 1, 1, 1);
  STG(1, 1, 2, 1); STG(1, 1, 3, 1);
  asm volatile("s_waitcnt vmcnt(6)" ::: "memory");
  __builtin_amdgcn_s_barrier();

  for (int g = 0; g < nt; ++g) {
    const int b = g & 1, nb = b ^ 1;
    short8 aR[4][2], bR[4][2];
    // phase 1
    #pragma unroll
    for (int mi = 0; mi < 4; ++mi) { aR[mi][0] = RDA(b, mi, 0); aR[mi][1] = RDA(b, mi, 1); }
    #pragma unroll
    for (int ni = 0; ni < 2; ++ni) { bR[ni][0] = RDB(b, ni, 0); bR[ni][1] = RDB(b, ni, 1); }
    if (g + 1 < nt) { STG(nb, 0, 1, g+1); STG(nb, 0, 3, g+1); }
    __builtin_amdgcn_s_barrier();
    LGKM0;
    __builtin_amdgcn_s_setprio(1);
    #pragma unroll
    for (int mi = 0; mi < 4; ++mi)
      #pragma unroll
      for (int ni = 0; ni < 2; ++ni) {
        MFMA16(acc[mi][ni], aR[mi][0], bR[ni][0]);
        MFMA16(acc[mi][ni], aR[mi][1], bR[ni][1]);
      }
    __builtin_amdgcn_s_setprio(0);
    __builtin_amdgcn_s_barrier();
    // phase 2
    #pragma unroll
    for (int ni = 2; ni < 4; ++ni) { bR[ni][0] = RDB(b, ni, 0); bR[ni][1] = RDB(b, ni, 1); }
    if (g + 2 < nt) { STG(b, 0, 0, g+2); STG(b, 0, 2, g+2); }
    __builtin_amdgcn_s_barrier();
    LGKM0;
    __builtin_amdgcn_s_setprio(1);
    #pragma unroll
    for (int mi = 0; mi < 4; ++mi)
      #pragma unroll
      for (int ni = 2; ni < 4; ++ni) {
        MFMA16(acc[mi][ni], aR[mi][0], bR[ni][0]);
        MFMA16(acc[mi][ni], aR[mi][1], bR[ni][1]);
      }
    __builtin_amdgcn_s_setprio(0);
    __builtin_amdgcn_s_barrier();
    // phase 3
    #pragma unroll
    for (int mi = 0; mi < 4; ++mi) { aR[mi][0] = RDA(b, mi+4, 0); aR[mi][1] = RDA(b, mi+4, 1); }
    if (g + 2 < nt) { STG(b, 1, 0, g+2); STG(b, 1, 1, g+2); }
    __builtin_amdgcn_s_barrier();
    LGKM0;
    __builtin_amdgcn_s_setprio(1);
    #pragma unroll
    for (int mi = 0; mi < 4; ++mi)
      #pragma unroll
      for (int ni = 0; ni < 2; ++ni) {
        MFMA16(acc[mi+4][ni], aR[mi][0], bR[ni][0]);
        MFMA16(acc[mi+4][ni], aR[mi][1], bR[ni][1]);
      }
    __builtin_amdgcn_s_setprio(0);
    __builtin_amdgcn_s_barrier();
    // phase 4
    if (g + 2 < nt) { STG(b, 1, 2, g+2); STG(b, 1, 3, g+2); }
    __builtin_amdgcn_s_setprio(1);
    #pragma unroll
    for (int mi = 0; mi < 4; ++mi)
      #pragma unroll
      for (int ni = 2; ni < 4; ++ni) {
        MFMA16(acc[mi+4][ni], aR[mi][0], bR[ni][0]);
        MFMA16(acc[mi+4][ni], aR[mi][1], bR[ni][1]);
      }
    __builtin_amdgcn_s_setprio(0);
    if (g + 1 < nt) {
      if (g + 2 < nt) asm volatile("s_waitcnt vmcnt(6)" ::: "memory");
      else            asm volatile("s_waitcnt vmcnt(0)" ::: "memory");
    }
    __builtin_amdgcn_s_barrier();
  }

  const float* bz = bias ? (bias + (long long)z * sBias) : nullptr;
  #pragma unroll
  for (int mi = 0; mi < 8; ++mi) {
    const int row = bm + wr*128 + mi*16 + lk*4;
    #pragma unroll
    for (int ni = 0; ni < 4; ++ni) {
      const int col = bn + wc*64 + ni*16 + lr;
      const float bval = bz ? bz[col] : 0.f;
      #pragma unroll
      for (int r = 0; r < 4; ++r) {
        float val = acc[mi][ni][r] * scale + bval;
        if (OUT_BF16)
          ((short*)Cv)[(long long)z*sC + (long long)(row + r) * N + col] = f2bf(val);
        else
          ((float*)Cv)[(long long)z*sC + (long long)(row + r) * N + col] = val;
      }
    }
  }
  #undef STG
  #undef RDA
  #undef RDB
}

// ============================================================================
// 256x128 GEMM, 3-buffer ring, stage-distance 2, ONE barrier per K-tile.
// Wave layout (WM,WN)=(4,2): per-wave 64x64 out, acc[4][4] — LDS read traffic
// 128 KB/tile (vs 160 KB at (2,4)). Halves split by K-step (ks0|ks1); per-acc
// accumulation order unchanged (ks0 then ks1). 3-buffer hazard proof as R3:
// STG for tile g+2 -> buf (g+2)%3, last read at tile g-1, >=1 barrier back;
// vmcnt(6) at tile end drains tile-(g+1)'s 6 loads. lda/ldb/ldc strides;
// BIAS_ROW: bias indexed by output row (for Wt-side A).
// ============================================================================
template<int OUT_BF16, int BIAS_ROW>
__global__ __launch_bounds__(512, 2) void gemm4_k(const short* __restrict__ A,
    const short* __restrict__ Bt, void* __restrict__ Cv,
    const float* __restrict__ bias,
    int K, int lda, int ldb, int ldc,
    long long sA, long long sB, long long sC, long long sBias,
    float scale, int gxs, int gys)
{
  __shared__ __align__(16) short lds[3][24576];  // per buf: A [0,16384) B [16384,24576)
  XCD_DECODE(gxs, gys);
  A  += (long long)z * sA;
  Bt += (long long)z * sB;
  const int bm = byi * 256;
  const int bn = bxi * 128;
  const int tid  = threadIdx.x;
  const int w    = tid >> 6, lane = tid & 63;
  const int wr   = w >> 1,   wc   = w & 1;     // (WM,WN) = (4,2)
  const int lr   = lane & 15, lk  = lane >> 4;

  const int rsw0 = ((lk    ) ^ (lr & 7)) * 8;
  const int rsw1 = ((lk + 4) ^ (lr & 7)) * 8;
  const int srow = w * 8 + (lane >> 3);
  const int swc  = ((lane & 7) ^ ((lane >> 3) & 7)) * 8;
  const short* gA[4]; const short* gB[2];
  #pragma unroll
  for (int i = 0; i < 4; ++i)
    gA[i] = A + (long long)(bm + i*64 + srow) * lda + swc;
  #pragma unroll
  for (int i = 0; i < 2; ++i)
    gB[i] = Bt + (long long)(bn + i*64 + srow) * ldb + swc;

  #define STGA(buf, i, kt) \
    __builtin_amdgcn_global_load_lds((gas1_t)(gA[i] + (long long)(kt)*64), \
        (las3_t)&lds[buf][(i)*4096 + w*512], 16, 0, 0)
  #define STGB(buf, i, kt) \
    __builtin_amdgcn_global_load_lds((gas1_t)(gB[i] + (long long)(kt)*64), \
        (las3_t)&lds[buf][16384 + (i)*4096 + w*512], 16, 0, 0)
  #define RDA4(buf, mi, ks) (*(const short8*)&lds[buf][(wr*64 + (mi)*16 + lr)*64 + ((ks) ? rsw1 : rsw0)])
  #define RDB4(buf, ni, ks) (*(const short8*)&lds[buf][16384 + (wc*64 + (ni)*16 + lr)*64 + ((ks) ? rsw1 : rsw0)])

  f32x4 acc[4][4] = {};
  const int nt = K >> 6;

  // prologue: stage tile0 -> buf0, tile1 -> buf1; wait tile0 (keep 6 in flight)
  STGA(0, 0, 0); STGA(0, 2, 0); STGB(0, 0, 0);
  STGB(0, 1, 0); STGA(0, 1, 0); STGA(0, 3, 0);
  STGA(1, 0, 1); STGA(1, 2, 1); STGB(1, 0, 1);
  STGB(1, 1, 1); STGA(1, 1, 1); STGA(1, 3, 1);
  asm volatile("s_waitcnt vmcnt(6)" ::: "memory");
  __builtin_amdgcn_s_barrier();

  int b = 0, nb = 2;
  for (int g = 0; g < nt; ++g) {
    short8 aR[4], bR[4];
    // ---- half 1: ks = 0 ----
    #pragma unroll
    for (int mi = 0; mi < 4; ++mi) aR[mi] = RDA4(b, mi, 0);
    #pragma unroll
    for (int ni = 0; ni < 4; ++ni) bR[ni] = RDB4(b, ni, 0);
    if (g + 2 < nt) { STGA(nb, 0, g+2); STGA(nb, 2, g+2); STGB(nb, 0, g+2); }
    LGKM0;
    __builtin_amdgcn_s_setprio(1);
    #pragma unroll
    for (int mi = 0; mi < 4; ++mi)
      #pragma unroll
      for (int ni = 0; ni < 4; ++ni)
        MFMA16(acc[mi][ni], aR[mi], bR[ni]);
    __builtin_amdgcn_s_setprio(0);
    // ---- half 2: ks = 1 ----
    #pragma unroll
    for (int mi = 0; mi < 4; ++mi) aR[mi] = RDA4(b, mi, 1);
    #pragma unroll
    for (int ni = 0; ni < 4; ++ni) bR[ni] = RDB4(b, ni, 1);
    if (g + 2 < nt) { STGB(nb, 1, g+2); STGA(nb, 1, g+2); STGA(nb, 3, g+2); }
    LGKM0;
    __builtin_amdgcn_s_setprio(1);
    #pragma unroll
    for (int mi = 0; mi < 4; ++mi)
      #pragma unroll
      for (int ni = 0; ni < 4; ++ni)
        MFMA16(acc[mi][ni], aR[mi], bR[ni]);
    __builtin_amdgcn_s_setprio(0);
    if (g + 2 < nt)      asm volatile("s_waitcnt vmcnt(6)" ::: "memory");
    else if (g + 1 < nt) asm volatile("s_waitcnt vmcnt(0)" ::: "memory");
    __builtin_amdgcn_s_barrier();
    b  = (b  == 2) ? 0 : b  + 1;
    nb = (nb == 2) ? 0 : nb + 1;
  }

  const float* bz = bias;
  #pragma unroll
  for (int mi = 0; mi < 4; ++mi) {
    const int row = bm + wr*64 + mi*16 + lk*4;
    #pragma unroll
    for (int ni = 0; ni < 4; ++ni) {
      const int col = bn + wc*64 + ni*16 + lr;
      const float bcol = (bz && !BIAS_ROW) ? bz[(long long)z*sBias + col] : 0.f;
      #pragma unroll
      for (int r = 0; r < 4; ++r) {
        float bval = BIAS_ROW ? bz[row + r] : bcol;
        float val = acc[mi][ni][r] * scale + bval;
        if (OUT_BF16)
          ((short*)Cv)[(long long)z*sC + (long long)(row + r) * ldc + col] = f2bf(val);
        else
          ((float*)Cv)[(long long)z*sC + (long long)(row + r) * ldc + col] = val;
      }
    }
  }
  #undef STGA
  #undef STGB
  #undef RDA4
  #undef RDB4
}

extern "C" void kernel_launch(void* const* d_in, const int* in_sizes, int n_in,
                              void* d_out, int out_size, void* d_ws, size_t ws_size,
                              hipStream_t stream) {
  const float* q  = (const float*)d_in[0];
  const float* k  = (const float*)d_in[1];
  const float* v  = (const float*)d_in[2];
  const float* Wq = (const float*)d_in[4];
  const float* bq = (const float*)d_in[5];
  const float* Wk = (const float*)d_in[6];
  const float* bk = (const float*)d_in[7];
  const float* Wv = (const float*)d_in[8];
  const float* bv = (const float*)d_in[9];
  const float* Wo = (const float*)d_in[10];
  const float* bo = (const float*)d_in[11];

  // ws layout (bytes), peak ~125.8 MB:
  char* w = (char*)d_ws;
  short* Wt     = (short*)(w);                  // [4][1024][1024] bf16 (W^T)   8,388,608
  float* biasb  = (float*)(w + 8388608);        // [4][1024] f32                   16,384
  short* QKV    = (short*)(w + 8404992);        // Q,K bf16 [2][4,2048,1024]
  short* qkvbf  = (short*)(w + 58736640);       // q,k,v bf16, dies after projections
  short* P      = (short*)(w + 58736640);       // scores/P bf16 [4,2048,2048] (reuses qkvbf)
  short* Vt     = (short*)(w + 92291072);       // [1024][8192] bf16 (d x (b,s)) 16,777,216
  short* xt     = (short*)(w + 109068288);      // [4][1024][2048] bf16          16,777,216

  short* Qp = QKV;
  short* Kp = QKV + 8388608LL;
  short* vbf = qkvbf + 16777216LL;

  // 1) convert inputs + weights, gather biases
  cvt_qkv_k<<<dim3(4096,1,3), 256, 0, stream>>>(q, k, v, qkvbf);
  bias_gather_k<<<dim3(16), 256, 0, stream>>>(bq, bk, bv, bo, biasb);
  wt_cvt_k<<<dim3(32,32,4), dim3(32,8), 0, stream>>>(Wq, Wk, Wv, Wo, Wt);

  // 2a) q,k projections via gemm8: grid = 4(N) x 32(M) x 2(z) = 256 = 1 round
  gemm8_k<1><<<256, 512, 0, stream>>>(qkvbf, Wt, QKV, biasb,
      8192, 1024, 1024, 8388608LL, 1048576LL, 8388608LL, 1024LL, 1.0f, 2, 5);

  // 2b) V projection, transposed output: Vt[d, bs] = Wv^T @ v_bf^T + bv[d]
  gemm4_k<1,1><<<256, 512, 0, stream>>>(Wt + 2097152LL, vbf, Vt, biasb + 2048,
      1024, 1024, 1024, 8192, 0LL, 0LL, 0LL, 0LL, 1.0f, 6, 2);

  // 3) scores = Q @ K^T / 32 -> bf16 P (256 blocks = 1 round)
  gemm8_k<1><<<256, 512, 0, stream>>>(Qp, Kp, P, nullptr,
      2048, 2048, 1024, 2097152LL, 2097152LL, 4194304LL, 0LL, 0.03125f, 3, 3);

  // 4) P = softmax_rows(P) in place
  softmax_bf_k<<<dim3(8192), 256, 0, stream>>>(P);

  // 5) xt[d, q] = Vt[d,:] . P[q,:]  (A = Vt + z*2048 cols, lda=8192)
  gemm4_k<1,0><<<256, 512, 0, stream>>>(Vt, P, xt, nullptr,
      2048, 8192, 2048, 2048, 2048LL, 4194304LL, 2097152LL, 0LL, 1.0f, 4, 2);

  // 6) out = reshape(xt) @ Wo + bo; xt reinterpreted [2048][1024] row-major per z
  gemm4_k<0,0><<<256, 512, 0, stream>>>(xt, Wt + 3145728LL, (float*)d_out,
      biasb + 3072, 1024, 1024, 1024, 1024, 2097152LL, 0LL, 2097152LL, 0LL, 1.0f, 3, 3);
}